// Round 5
// baseline (560.521 us; speedup 1.0000x reference)
//
#include <hip/hip_runtime.h>
#include <hip/hip_bf16.h>
#include <math.h>

#define N_NODE 40000
#define EMB 100
#define BB 512
#define LL 50
#define NI 50
#define EDG 800000
#define SCAN_BLOCKS 157  // ceil(40000/256)

typedef short s16x8 __attribute__((ext_vector_type(8)));   // 8 bf16 = 4 VGPRs
typedef float f32x4 __attribute__((ext_vector_type(4)));   // MFMA 16x16 accumulator

// ---------------- CSR build ----------------
__global__ void khist(const int* __restrict__ rows, int* __restrict__ counts) {
  int e = blockIdx.x * 256 + threadIdx.x;
  atomicAdd(&counts[rows[e]], 1);
}

// block-local exclusive scan (256 elems/block) + block sums
__global__ __launch_bounds__(256) void kscan1(const int* __restrict__ counts,
                                              int* __restrict__ scanout,
                                              int* __restrict__ blocksums, int n) {
  __shared__ int wsum[4];
  int tid = threadIdx.x;
  int i = blockIdx.x * 256 + tid;
  int v = (i < n) ? counts[i] : 0;
  int x = v;
  #pragma unroll
  for (int off = 1; off < 64; off <<= 1) {
    int t = __shfl_up(x, off, 64);
    if ((tid & 63) >= off) x += t;
  }
  int w = tid >> 6, lane = tid & 63;
  if (lane == 63) wsum[w] = x;
  __syncthreads();
  int woff = 0;
  #pragma unroll
  for (int k = 0; k < 4; ++k) woff += (k < w) ? wsum[k] : 0;
  int incl = x + woff;
  if (i < n) scanout[i] = incl - v;  // block-local exclusive
  if (tid == 255) blocksums[blockIdx.x] = incl;
}

// scan the block sums (one block, 256 threads >= 157)
__global__ __launch_bounds__(256) void kscan2(int* __restrict__ blocksums, int nb) {
  __shared__ int wsum[4];
  int tid = threadIdx.x;
  int v = (tid < nb) ? blocksums[tid] : 0;
  int x = v;
  #pragma unroll
  for (int off = 1; off < 64; off <<= 1) {
    int t = __shfl_up(x, off, 64);
    if ((tid & 63) >= off) x += t;
  }
  int w = tid >> 6, lane = tid & 63;
  if (lane == 63) wsum[w] = x;
  __syncthreads();
  int woff = 0;
  #pragma unroll
  for (int k = 0; k < 4; ++k) woff += (k < w) ? wsum[k] : 0;
  if (tid < nb) blocksums[tid] = x + woff - v;  // exclusive
}

// add block offsets, produce starts + cursor
__global__ __launch_bounds__(256) void kscan3(const int* __restrict__ scanout,
                                              const int* __restrict__ blocksums,
                                              int* __restrict__ starts,
                                              int* __restrict__ cursor, int n) {
  int i = blockIdx.x * 256 + threadIdx.x;
  if (i < n) {
    int s = scanout[i] + blocksums[blockIdx.x];
    starts[i] = s;
    cursor[i] = s;
  }
}

// fill: 4 edges/thread (4 independent atomic chains in flight), single int2
// scatter per edge (was 2x 4B to two arrays -> 2 dirtied lines; now 1).
__global__ __launch_bounds__(256) void kfill(const int* __restrict__ rows,
                                             const int* __restrict__ cols,
                                             const float* __restrict__ vals,
                                             int* __restrict__ cursor,
                                             int2* __restrict__ colval) {
  int e0 = (blockIdx.x * 256 + threadIdx.x) * 4;
  #pragma unroll
  for (int k = 0; k < 4; ++k) {
    int e = e0 + k;
    if (e < EDG) {
      int r = rows[e];
      int p = atomicAdd(&cursor[r], 1);
      int2 cv; cv.x = cols[e]; cv.y = __float_as_int(vals[e]);
      colval[p] = cv;
    }
  }
}

// ---------------- gather SpMM (wave per row, batched edges + 8x MLP) ----------
__global__ __launch_bounds__(256) void kspmm(const int* __restrict__ starts,
                                             const int* __restrict__ counts,
                                             const int2* __restrict__ colval,
                                             const float* __restrict__ x,
                                             float* __restrict__ out) {
  int row = blockIdx.x * 4 + (threadIdx.x >> 6);
  int lane = threadIdx.x & 63;
  int s = starts[row], cnt = counts[row];
  bool act = lane < 50;
  int d2 = (act ? lane : 49) * 2;      // clamped: inactive lanes re-read last pair
  float ax = 0.f, ay = 0.f;
  for (int base = 0; base < cnt; base += 64) {
    int nb = cnt - base; if (nb > 64) nb = 64;
    int cl = 0; float vl = 0.f;
    if (lane < nb) {
      int2 cv = colval[s + base + lane];
      cl = cv.x; vl = __int_as_float(cv.y);
    }
    int t = 0;
    for (; t + 8 <= nb; t += 8) {
      int c0 = __shfl(cl, t),     c1 = __shfl(cl, t + 1);
      int c2 = __shfl(cl, t + 2), c3 = __shfl(cl, t + 3);
      int c4 = __shfl(cl, t + 4), c5 = __shfl(cl, t + 5);
      int c6 = __shfl(cl, t + 6), c7 = __shfl(cl, t + 7);
      float v0 = __shfl(vl, t),     v1 = __shfl(vl, t + 1);
      float v2 = __shfl(vl, t + 2), v3 = __shfl(vl, t + 3);
      float v4 = __shfl(vl, t + 4), v5 = __shfl(vl, t + 5);
      float v6 = __shfl(vl, t + 6), v7 = __shfl(vl, t + 7);
      float2 g0 = *(const float2*)(x + (size_t)c0 * EMB + d2);
      float2 g1 = *(const float2*)(x + (size_t)c1 * EMB + d2);
      float2 g2 = *(const float2*)(x + (size_t)c2 * EMB + d2);
      float2 g3 = *(const float2*)(x + (size_t)c3 * EMB + d2);
      float2 g4 = *(const float2*)(x + (size_t)c4 * EMB + d2);
      float2 g5 = *(const float2*)(x + (size_t)c5 * EMB + d2);
      float2 g6 = *(const float2*)(x + (size_t)c6 * EMB + d2);
      float2 g7 = *(const float2*)(x + (size_t)c7 * EMB + d2);
      ax += v0 * g0.x; ay += v0 * g0.y;
      ax += v1 * g1.x; ay += v1 * g1.y;
      ax += v2 * g2.x; ay += v2 * g2.y;
      ax += v3 * g3.x; ay += v3 * g3.y;
      ax += v4 * g4.x; ay += v4 * g4.y;
      ax += v5 * g5.x; ay += v5 * g5.y;
      ax += v6 * g6.x; ay += v6 * g6.y;
      ax += v7 * g7.x; ay += v7 * g7.y;
    }
    for (; t + 4 <= nb; t += 4) {
      int c0 = __shfl(cl, t),     c1 = __shfl(cl, t + 1);
      int c2 = __shfl(cl, t + 2), c3 = __shfl(cl, t + 3);
      float v0 = __shfl(vl, t),     v1 = __shfl(vl, t + 1);
      float v2 = __shfl(vl, t + 2), v3 = __shfl(vl, t + 3);
      float2 g0 = *(const float2*)(x + (size_t)c0 * EMB + d2);
      float2 g1 = *(const float2*)(x + (size_t)c1 * EMB + d2);
      float2 g2 = *(const float2*)(x + (size_t)c2 * EMB + d2);
      float2 g3 = *(const float2*)(x + (size_t)c3 * EMB + d2);
      ax += v0 * g0.x; ay += v0 * g0.y;
      ax += v1 * g1.x; ay += v1 * g1.y;
      ax += v2 * g2.x; ay += v2 * g2.y;
      ax += v3 * g3.x; ay += v3 * g3.y;
    }
    for (; t < nb; ++t) {
      int c = __shfl(cl, t);
      float v = __shfl(vl, t);
      float2 g = *(const float2*)(x + (size_t)c * EMB + d2);
      ax += v * g.x; ay += v * g.y;
    }
  }
  if (act) {
    float2 o; o.x = ax; o.y = ay;
    *(float2*)(out + (size_t)row * EMB + d2) = o;
  }
}

// ---------------- l2norm-combine (item conv epilogue) ----------------
__global__ void kcomb(const float* __restrict__ x0, const float* __restrict__ x1,
                      const float* __restrict__ x2, const float* __restrict__ bI,
                      float* __restrict__ emb) {
  int n = blockIdx.x * 4 + (threadIdx.x >> 6);
  int lane = threadIdx.x & 63;
  int d0 = lane, d1 = lane + 64;
  bool h1 = d1 < EMB;
  size_t base = (size_t)n * EMB;
  float v00 = x0[base + d0], v01 = h1 ? x0[base + d1] : 0.f;
  float v10 = x1[base + d0], v11 = h1 ? x1[base + d1] : 0.f;
  float v20 = x2[base + d0], v21 = h1 ? x2[base + d1] : 0.f;
  float q0 = v00 * v00 + v01 * v01;
  float q1 = v10 * v10 + v11 * v11;
  float q2 = v20 * v20 + v21 * v21;
  #pragma unroll
  for (int off = 32; off; off >>= 1) {
    q0 += __shfl_xor(q0, off);
    q1 += __shfl_xor(q1, off);
    q2 += __shfl_xor(q2, off);
  }
  float r0 = 1.f / fmaxf(sqrtf(q0), 1e-12f);
  float r1 = 1.f / fmaxf(sqrtf(q1), 1e-12f);
  float r2 = 1.f / fmaxf(sqrtf(q2), 1e-12f);
  float b0 = bI[0], b1 = bI[1], b2 = bI[2];
  emb[base + d0] = b0 * v00 * r0 + b1 * v10 * r1 + b2 * v20 * r2;
  if (h1) emb[base + d1] = b0 * v01 * r0 + b1 * v11 * r1 + b2 * v21 * r2;
}

// ---------------- GAT v4: lane = output row, h-row in registers ----------------
__global__ __launch_bounds__(256) void kgat(
    const float* __restrict__ emb, const int* __restrict__ items,
    const int* __restrict__ adj,
    const float* __restrict__ a0p, const float* __restrict__ a1p,
    const float* __restrict__ a2p, const float* __restrict__ a3p,
    float* __restrict__ hgat) {
  __shared__ __align__(16) float hl[64 * 108];     // 27.6 KB, rows 50..63 zeroed
  __shared__ __align__(16) float as[4 * 100];      // 1.6 KB
  __shared__ float alpha_lds[64 * 51];             // 13.1 KB
  __shared__ float wred[4][2][64];                 // 2 KB
  int b = blockIdx.x;
  int tid = threadIdx.x;
  for (int idx = tid; idx < 400; idx += 256) {
    int k = idx / 100, d = idx % 100;
    const float* ap = (k == 0) ? a0p : (k == 1) ? a1p : (k == 2) ? a2p : a3p;
    as[idx] = ap[d];
  }
  for (int idx = tid; idx < 64 * 50; idx += 256) {
    int i = idx / 50, d2 = (idx % 50) * 2;
    float2 v; v.x = 0.f; v.y = 0.f;
    if (i < NI) {
      int node = items[b * NI + i];
      if (node != 0) v = *(const float2*)(emb + (size_t)(node - 1) * EMB + d2);
    }
    *(float2*)&hl[i * 108 + d2] = v;
  }
  __syncthreads();
  int w = tid >> 6, lane = tid & 63;
  int j0 = w * 13;
  int nj = 50 - j0; if (nj > 13) nj = 13;          // 13,13,13,11

  // my h-row into registers (lanes >=50 read zeroed rows -> e = 0, harmless)
  float4 hreg[25];
  #pragma unroll
  for (int q = 0; q < 25; ++q) hreg[q] = *(const float4*)&hl[lane * 108 + q * 4];

  // adj row slice (clamp lane to stay in-bounds for lanes 50..63)
  int al_lane = (lane < NI) ? lane : NI - 1;
  const int* adjrow = adj + (size_t)b * (NI * NI) + al_lane * NI + j0;
  int adjv[13];
  #pragma unroll
  for (int t = 0; t < 13; ++t) adjv[t] = (t < nj) ? adjrow[t] : 0;

  // ---- scores: e[jj] for my row vs j0+jj ----
  float e[13];
  #pragma unroll
  for (int jj = 0; jj < 13; ++jj) {
    float acc = 0.f;
    if (jj < nj) {
      int j = j0 + jj;
      int k = adjv[jj] - 1; k = (k < 0) ? 0 : (k > 3) ? 3 : k;
      const float* aw = &as[k * 100];
      #pragma unroll
      for (int q = 0; q < 25; ++q) {
        float4 hj = *(const float4*)&hl[j * 108 + q * 4];   // uniform broadcast
        float4 a4 = *(const float4*)(aw + q * 4);           // <=4 distinct addrs
        float4 hm = hreg[q];
        acc += hm.x * hj.x * a4.x + hm.y * hj.y * a4.y
             + hm.z * hj.z * a4.z + hm.w * hj.w * a4.w;
      }
      acc = (acc >= 0.f) ? acc : 0.2f * acc;     // leakyrelu
      acc = (adjv[jj] == 0) ? -9e15f : acc;      // mask (matches reference)
    } else {
      acc = -INFINITY;                           // excluded from max/sum
    }
    e[jj] = acc;
  }

  // ---- softmax across waves (per-lane row-local) ----
  float mloc = -INFINITY;
  #pragma unroll
  for (int jj = 0; jj < 13; ++jj) if (jj < nj) mloc = fmaxf(mloc, e[jj]);
  wred[w][0][lane] = mloc;
  __syncthreads();
  float m = fmaxf(fmaxf(wred[0][0][lane], wred[1][0][lane]),
                  fmaxf(wred[2][0][lane], wred[3][0][lane]));
  float sloc = 0.f;
  #pragma unroll
  for (int jj = 0; jj < 13; ++jj) if (jj < nj) {
    e[jj] = expf(e[jj] - m);
    sloc += e[jj];
  }
  wred[w][1][lane] = sloc;
  __syncthreads();
  float s = (wred[0][1][lane] + wred[1][1][lane]) +
            (wred[2][1][lane] + wred[3][1][lane]);
  float inv = 1.f / s;
  #pragma unroll
  for (int jj = 0; jj < 13; ++jj) if (jj < nj)
    alpha_lds[lane * 51 + j0 + jj] = e[jj] * inv;
  __syncthreads();

  // ---- PV: out[i][d] = sum_j alpha[i][j] * h[j][d]; wave w owns quads w+4t ----
  int nq = (w == 0) ? 7 : 6;
  float4 outq[7];
  #pragma unroll
  for (int t = 0; t < 7; ++t) outq[t] = make_float4(0.f, 0.f, 0.f, 0.f);
  for (int j = 0; j < NI; ++j) {
    float aj = alpha_lds[lane * 51 + j];        // stride 51 -> conflict-free
    #pragma unroll
    for (int t = 0; t < 7; ++t) {
      if (t < nq) {
        int q = w + 4 * t;
        float4 hv = *(const float4*)&hl[j * 108 + q * 4];   // uniform broadcast
        outq[t].x += aj * hv.x; outq[t].y += aj * hv.y;
        outq[t].z += aj * hv.z; outq[t].w += aj * hv.w;
      }
    }
  }
  if (lane < NI) {
    #pragma unroll
    for (int t = 0; t < 7; ++t) {
      if (t < nq) {
        int q = w + 4 * t;
        *(float4*)&hgat[((size_t)b * NI + lane) * EMB + q * 4] = outq[t];
      }
    }
  }
}

// ---------------- get_seq mix ----------------
__global__ void kseq(const float* __restrict__ emb, const int* __restrict__ rev,
                     const int* __restrict__ alias, const float* __restrict__ hgat,
                     float* __restrict__ hseq) {
  int idx = blockIdx.x * 256 + threadIdx.x;  // 2,560,000 exact
  int b = idx / 5000, r = idx % 5000, l = r / 100, d = r % 100;
  int node = rev[b * LL + l];
  float sh = (node == 0) ? 0.f : emb[(size_t)(node - 1) * EMB + d];
  int a = alias[b * LL + l];
  float shh = hgat[((size_t)b * NI + a) * EMB + d];
  hseq[idx] = 0.2f * sh + 0.8f * shh;
}

// ---------------- weight prep: transposes + pos@W1a ----------------
__global__ void kprep_t(const float* __restrict__ w1W, const float* __restrict__ g1W,
                        const float* __restrict__ g2W, float* __restrict__ w1t2,
                        float* __restrict__ g1t, float* __restrict__ g2t) {
  int idx = blockIdx.x * 256 + threadIdx.x;
  if (idx >= 10000) return;
  int c = idx / 100, o = idx % 100;
  w1t2[c * 100 + o] = w1W[o * 200 + 100 + c];
  g1t[c * 100 + o] = g1W[o * 100 + c];
  g2t[c * 100 + o] = g2W[o * 100 + c];
}

__global__ void kprep_pos(const float* __restrict__ posE, const float* __restrict__ w1W,
                          const float* __restrict__ w1b, float* __restrict__ posW) {
  int idx = blockIdx.x * 256 + threadIdx.x;
  if (idx >= 5000) return;
  int l = idx / 100, o = idx % 100;
  float acc = w1b[o];
  for (int c = 0; c < 100; ++c) acc += posE[l * 100 + c] * w1W[o * 200 + c];
  posW[idx] = acc;
}

// ---------------- soft attention (block per batch, register-tiled) ----------------
__global__ __launch_bounds__(256) void ksoft(
    const float* __restrict__ hseqG, const float* __restrict__ slenp,
    const int* __restrict__ maskp,
    const float* __restrict__ posW, const float* __restrict__ w1t2,
    const float* __restrict__ glu1t, const float* __restrict__ glu1b,
    const float* __restrict__ glu2t, const float* __restrict__ w2,
    float* __restrict__ sel) {
  __shared__ float hq[LL * 101];       // 20.2 KB
  __shared__ float nh[LL * 100];       // 20 KB
  __shared__ float red[25 * 52];       // 5.2 KB  (red[og][l])
  __shared__ float hs_s[100];
  __shared__ float g_s[100];
  __shared__ float beta_s[LL];
  int b = blockIdx.x, tid = threadIdx.x;
  for (int idx = tid; idx < LL * 100; idx += 256) {
    int l = idx / 100, d = idx % 100;
    hq[l * 101 + d] = hseqG[((size_t)b * LL + l) * 100 + d];
  }
  __syncthreads();
  if (tid < 100) {
    float s = 0.f;
    for (int l = 0; l < LL; ++l) s += hq[l * 101 + tid];
    hs_s[tid] = s / slenp[b];
  }
  __syncthreads();
  if (tid < 100) {
    float acc = 0.f;
    for (int c = 0; c < 100; ++c) acc += hs_s[c] * glu2t[c * 100 + tid];
    g_s[tid] = acc;
  }
  // ---- phase B: nh = tanh(hq @ w1t2 + posW) ----
  int lg = tid / 25, og = tid % 25;    // valid when tid < 250
  if (tid < 250) {
    float acc[5][4];
    #pragma unroll
    for (int j = 0; j < 5; ++j) {
      float4 p = *(const float4*)&posW[(lg * 5 + j) * 100 + og * 4];
      acc[j][0] = p.x; acc[j][1] = p.y; acc[j][2] = p.z; acc[j][3] = p.w;
    }
    for (int c = 0; c < 100; ++c) {
      float4 wv = *(const float4*)&w1t2[c * 100 + og * 4];
      float hv[5];
      #pragma unroll
      for (int j = 0; j < 5; ++j) hv[j] = hq[(lg * 5 + j) * 101 + c];
      #pragma unroll
      for (int j = 0; j < 5; ++j) {
        acc[j][0] += hv[j] * wv.x;
        acc[j][1] += hv[j] * wv.y;
        acc[j][2] += hv[j] * wv.z;
        acc[j][3] += hv[j] * wv.w;
      }
    }
    #pragma unroll
    for (int j = 0; j < 5; ++j) {
      float4 t;
      t.x = tanhf(acc[j][0]); t.y = tanhf(acc[j][1]);
      t.z = tanhf(acc[j][2]); t.w = tanhf(acc[j][3]);
      *(float4*)&nh[(lg * 5 + j) * 100 + og * 4] = t;
    }
  }
  __syncthreads();  // nh + g_s visible
  // ---- phase C: val = sigmoid(nh @ glu1t + g + b) * w2; row-sum -> red ----
  if (tid < 250) {
    float4 gb = *(const float4*)&glu1b[og * 4];
    float4 gg = *(const float4*)&g_s[og * 4];
    float base0 = gg.x + gb.x, base1 = gg.y + gb.y, base2 = gg.z + gb.z, base3 = gg.w + gb.w;
    float acc[5][4];
    #pragma unroll
    for (int j = 0; j < 5; ++j) {
      acc[j][0] = base0; acc[j][1] = base1; acc[j][2] = base2; acc[j][3] = base3;
    }
    for (int c = 0; c < 100; ++c) {
      float4 wv = *(const float4*)&glu1t[c * 100 + og * 4];
      float hv[5];
      #pragma unroll
      for (int j = 0; j < 5; ++j) hv[j] = nh[(lg * 5 + j) * 100 + c];
      #pragma unroll
      for (int j = 0; j < 5; ++j) {
        acc[j][0] += hv[j] * wv.x;
        acc[j][1] += hv[j] * wv.y;
        acc[j][2] += hv[j] * wv.z;
        acc[j][3] += hv[j] * wv.w;
      }
    }
    float4 w2v = *(const float4*)&w2[og * 4];
    #pragma unroll
    for (int j = 0; j < 5; ++j) {
      float s0 = w2v.x / (1.f + expf(-acc[j][0]));
      float s1 = w2v.y / (1.f + expf(-acc[j][1]));
      float s2 = w2v.z / (1.f + expf(-acc[j][2]));
      float s3 = w2v.w / (1.f + expf(-acc[j][3]));
      red[og * 52 + lg * 5 + j] = (s0 + s1) + (s2 + s3);
    }
  }
  __syncthreads();
  if (tid < LL) {
    float s = 0.f;
    for (int og2 = 0; og2 < 25; ++og2) s += red[og2 * 52 + tid];
    beta_s[tid] = s * (float)maskp[b * LL + tid];
  }
  __syncthreads();
  if (tid < 100) {
    float acc = 0.f;
    for (int l = 0; l < LL; ++l) acc += beta_s[l] * hq[l * 101 + tid];
    sel[(size_t)b * 100 + tid] = acc;
  }
}

// ---------------- session conv: dense [512,512] @ [512,100] ----------------
__global__ void ksess(const float* __restrict__ adjS, const float* __restrict__ x,
                      float* __restrict__ out) {
  int b = blockIdx.x, d = threadIdx.x;
  if (d >= 100) return;
  const float* ar = adjS + (size_t)b * BB;
  float a0 = 0.f, a1 = 0.f, a2 = 0.f, a3 = 0.f;
  for (int j = 0; j < BB; j += 4) {
    a0 += ar[j]     * x[(j)     * 100 + d];
    a1 += ar[j + 1] * x[(j + 1) * 100 + d];
    a2 += ar[j + 2] * x[(j + 2) * 100 + d];
    a3 += ar[j + 3] * x[(j + 3) * 100 + d];
  }
  out[(size_t)b * 100 + d] = (a0 + a1) + (a2 + a3);
}

__global__ void ksesscomb(const float* __restrict__ x0, const float* __restrict__ x1,
                          const float* __restrict__ x2, const float* __restrict__ aS,
                          float* __restrict__ out) {
  int b = blockIdx.x * 4 + (threadIdx.x >> 6);
  int lane = threadIdx.x & 63;
  int d0 = lane, d1 = lane + 64;
  bool h1 = d1 < EMB;
  size_t base = (size_t)b * EMB;
  float v00 = x0[base + d0], v01 = h1 ? x0[base + d1] : 0.f;
  float v10 = x1[base + d0], v11 = h1 ? x1[base + d1] : 0.f;
  float v20 = x2[base + d0], v21 = h1 ? x2[base + d1] : 0.f;
  float q0 = v00 * v00 + v01 * v01;
  float q1 = v10 * v10 + v11 * v11;
  float q2 = v20 * v20 + v21 * v21;
  #pragma unroll
  for (int off = 32; off; off >>= 1) {
    q0 += __shfl_xor(q0, off);
    q1 += __shfl_xor(q1, off);
    q2 += __shfl_xor(q2, off);
  }
  float r0 = 1.f / fmaxf(sqrtf(q0), 1e-12f);
  float r1 = 1.f / fmaxf(sqrtf(q1), 1e-12f);
  float r2 = 1.f / fmaxf(sqrtf(q2), 1e-12f);
  float b0 = aS[0], b1 = aS[1], b2 = aS[2];
  // seq_h = sel1+sel2 = 2 * session_conv output
  out[base + d0] = 2.f * (b0 * v00 * r0 + b1 * v10 * r1 + b2 * v20 * r2);
  if (h1) out[base + d1] = 2.f * (b0 * v01 * r0 + b1 * v11 * r1 + b2 * v21 * r2);
}

// ---------------- bf16 hi/lo split prep ----------------
// B = 2*emb_gnn -> [40000][128] padded; A = seqh -> [512][128] padded
__global__ void kprepB(const float* __restrict__ emb, unsigned short* __restrict__ bHi,
                       unsigned short* __restrict__ bLo) {
  int idx = blockIdx.x * 256 + threadIdx.x;  // 5,120,000 exact
  int n = idx >> 7, k = idx & 127;
  float v = (k < EMB) ? 2.f * emb[(size_t)n * EMB + k] : 0.f;
  __hip_bfloat16 h = __float2bfloat16(v);
  float rem = v - __bfloat162float(h);
  __hip_bfloat16 l = __float2bfloat16(rem);
  bHi[idx] = *reinterpret_cast<unsigned short*>(&h);
  bLo[idx] = *reinterpret_cast<unsigned short*>(&l);
}

__global__ void kprepA(const float* __restrict__ seqh, unsigned short* __restrict__ aHi,
                       unsigned short* __restrict__ aLo) {
  int idx = blockIdx.x * 256 + threadIdx.x;  // 65,536 exact
  int n = idx >> 7, k = idx & 127;
  float v = (k < EMB) ? seqh[(size_t)n * EMB + k] : 0.f;
  __hip_bfloat16 h = __float2bfloat16(v);
  float rem = v - __bfloat162float(h);
  __hip_bfloat16 l = __float2bfloat16(rem);
  aHi[idx] = *reinterpret_cast<unsigned short*>(&h);
  aLo[idx] = *reinterpret_cast<unsigned short*>(&l);
}

// ---------------- scores GEMM v2: B staged ONCE, b-loop inside ----------------
// Was grid (625,8): every 64n B tile fetched by 8 b-blocks -> FETCH 81 MB.
// Now grid (1250): 32n cols/block, loop b0 over all 512 A rows with B in LDS.
// A (256 KB hi+lo) stays L2-resident across the loop.
__global__ __launch_bounds__(256) void kscoresM(
    const unsigned short* __restrict__ aHi, const unsigned short* __restrict__ aLo,
    const unsigned short* __restrict__ bHi, const unsigned short* __restrict__ bLo,
    float* __restrict__ outS) {
  __shared__ __align__(16) unsigned short Bh[32 * 136];  // 136 = 128 + 8 pad
  __shared__ __align__(16) unsigned short Bl[32 * 136];
  int tid = threadIdx.x;
  int n0 = blockIdx.x * 32;
  int w = tid >> 6, lane = tid & 63;
  int ln = lane & 15, quad = lane >> 4;

  // stage B tile (32 rows x 128 k, hi+lo) into LDS
  #pragma unroll
  for (int it = 0; it < 2; ++it) {
    int seg = tid + it * 256;      // 0..511
    int r = seg >> 4, q = seg & 15;
    *(s16x8*)&Bh[r * 136 + q * 8] = *(const s16x8*)&bHi[(size_t)(n0 + r) * 128 + q * 8];
    *(s16x8*)&Bl[r * 136 + q * 8] = *(const s16x8*)&bLo[(size_t)(n0 + r) * 128 + q * 8];
  }
  __syncthreads();

  for (int b0 = 0; b0 < BB; b0 += 64) {
    const unsigned short* aRowH = aHi + (size_t)(b0 + w * 16 + ln) * 128 + quad * 8;
    const unsigned short* aRowL = aLo + (size_t)(b0 + w * 16 + ln) * 128 + quad * 8;
    s16x8 ah[4], al[4];
    #pragma unroll
    for (int s = 0; s < 4; ++s) {
      ah[s] = *(const s16x8*)(aRowH + s * 32);
      al[s] = *(const s16x8*)(aRowL + s * 32);
    }
    f32x4 acc[2];
    #pragma unroll
    for (int t = 0; t < 2; ++t) acc[t] = (f32x4){0.f, 0.f, 0.f, 0.f};
    #pragma unroll
    for (int s = 0; s < 4; ++s) {
      #pragma unroll
      for (int t = 0; t < 2; ++t) {
        s16x8 bh = *(const s16x8*)&Bh[(t * 16 + ln) * 136 + s * 32 + quad * 8];
        s16x8 bl = *(const s16x8*)&Bl[(t * 16 + ln) * 136 + s * 32 + quad * 8];
        acc[t] = __builtin_amdgcn_mfma_f32_16x16x32_bf16(ah[s], bh, acc[t], 0, 0, 0);
        acc[t] = __builtin_amdgcn_mfma_f32_16x16x32_bf16(al[s], bh, acc[t], 0, 0, 0);
        acc[t] = __builtin_amdgcn_mfma_f32_16x16x32_bf16(ah[s], bl, acc[t], 0, 0, 0);
      }
    }
    int brow = b0 + w * 16 + quad * 4;
    #pragma unroll
    for (int t = 0; t < 2; ++t) {
      int ncol = n0 + t * 16 + ln;
      #pragma unroll
      for (int r = 0; r < 4; ++r) {
        outS[(size_t)(brow + r) * N_NODE + ncol] = acc[t][r];
      }
    }
  }
}

// ---------------- per-row logsumexp + target score ----------------
__global__ __launch_bounds__(256) void klse(const float* __restrict__ outS,
                                            const int* __restrict__ tar,
                                            float* __restrict__ part) {
  __shared__ float ms[256], ss[256];
  int b = blockIdx.x, tid = threadIdx.x;
  const float2* sp = (const float2*)(outS + (size_t)b * N_NODE);
  float m = -INFINITY, s = 0.f;
  for (int i = tid; i < N_NODE / 2; i += 256) {
    float2 v = sp[i];
    float mx = fmaxf(v.x, v.y);
    float add = expf(v.x - mx) + expf(v.y - mx);
    if (mx > m) { s = s * expf(m - mx) + add; m = mx; }
    else s += add * expf(mx - m);
  }
  ms[tid] = m; ss[tid] = s;
  __syncthreads();
  for (int st = 128; st; st >>= 1) {
    if (tid < st) {
      float m2 = ms[tid + st], s2 = ss[tid + st];
      float M = fmaxf(ms[tid], m2);
      ss[tid] = ss[tid] * expf(ms[tid] - M) + s2 * expf(m2 - M);
      ms[tid] = M;
    }
    __syncthreads();
  }
  if (tid == 0) {
    float tsc = outS[(size_t)b * N_NODE + tar[b]];
    part[b] = tsc - (ms[0] + logf(ss[0]));
  }
}

__global__ void kfinal(const float* __restrict__ part, float* __restrict__ out) {
  __shared__ float red[256];
  int tid = threadIdx.x;
  red[tid] = part[tid] + part[tid + 256];
  __syncthreads();
  for (int st = 128; st; st >>= 1) {
    if (tid < st) red[tid] += red[tid + st];
    __syncthreads();
  }
  if (tid == 0) {
    out[0] = 0.f;                        // con_loss
    out[1] = -red[0] / (float)BB;        // loss
  }
}

extern "C" void kernel_launch(void* const* d_in, const int* in_sizes, int n_in,
                              void* d_out, int out_size, void* d_ws, size_t ws_size,
                              hipStream_t stream) {
  const int* tar    = (const int*)d_in[0];
  const int* rev    = (const int*)d_in[1];
  const int* maskp  = (const int*)d_in[2];
  const float* slen = (const float*)d_in[3];
  const float* sadj = (const float*)d_in[4];
  const int* items  = (const int*)d_in[6];
  const int* adjp   = (const int*)d_in[7];
  const int* alias  = (const int*)d_in[8];
  const int* grows  = (const int*)d_in[9];
  const int* gcols  = (const int*)d_in[10];
  const float* gvals = (const float*)d_in[11];
  const float* nemb = (const float*)d_in[12];
  const float* bI   = (const float*)d_in[13];
  const float* aS   = (const float*)d_in[14];
  const float* a0p  = (const float*)d_in[15];
  const float* a1p  = (const float*)d_in[16];
  const float* a2p  = (const float*)d_in[17];
  const float* a3p  = (const float*)d_in[18];
  const float* w1W  = (const float*)d_in[19];
  const float* w1b  = (const float*)d_in[20];
  const float* w2p  = (const float*)d_in[21];
  const float* g1W  = (const float*)d_in[22];
  const float* g1b  = (const float*)d_in[23];
  const float* g2W  = (const float*)d_in[24];
  const float* posE = (const float*)d_in[25];

  float* W = (float*)d_ws;
  size_t o = 0;
  float* emb_gnn = W + o; o += (size_t)N_NODE * EMB;   // 4,000,000
  float* x1      = W + o; o += (size_t)N_NODE * EMB;   // reused: hgat, then bHi
  float* x2      = W + o; o += (size_t)N_NODE * EMB;   // reused: hseq, then bLo
  float* sel     = W + o; o += (size_t)BB * EMB;
  float* y1      = W + o; o += (size_t)BB * EMB;
  float* y2      = W + o; o += (size_t)BB * EMB;
  float* seqh    = W + o; o += (size_t)BB * EMB;
  float* posW    = W + o; o += 5120;
  float* w1t2    = W + o; o += 10000;
  float* glu1t   = W + o; o += 10000;
  float* glu2t   = W + o; o += 10000;
  int2* colval   = (int2*)(W + o); o += (size_t)2 * EDG;  // merged {col,val}
  float* part    = W + o; o += 512;
  int* counts = (int*)(W + o); o += N_NODE;
  int* starts = (int*)(W + o); o += N_NODE;
  int* cursor = (int*)(W + o); o += N_NODE;
  int* scantmp = (int*)(W + o); o += N_NODE;
  int* blocksums = (int*)(W + o); o += 256;
  unsigned short* aHi = (unsigned short*)(W + o); o += 32768;  // 512*128 bf16 = 32768 floats/2
  unsigned short* aLo = (unsigned short*)(W + o); o += 32768;
  // hgat/hseq alias x1/x2 (dead after kcomb); bHi/bLo alias x1/x2 (hgat dead after
  // kseq, hseq dead after ksoft; each needs 2.56M floats of the 4M region)
  float* hgat = x1;
  float* hseq = x2;
  unsigned short* bHi = (unsigned short*)x1;   // 5.12M u16 = 2.56M floats <= 4M
  unsigned short* bLo = (unsigned short*)x2;

  float* outF = (float*)d_out;
  float* outScores = outF + 2;

  hipMemsetAsync(counts, 0, N_NODE * sizeof(int), stream);
  khist<<<EDG / 256, 256, 0, stream>>>(grows, counts);
  kscan1<<<SCAN_BLOCKS, 256, 0, stream>>>(counts, scantmp, blocksums, N_NODE);
  kscan2<<<1, 256, 0, stream>>>(blocksums, SCAN_BLOCKS);
  kscan3<<<SCAN_BLOCKS, 256, 0, stream>>>(scantmp, blocksums, starts, cursor, N_NODE);
  kfill<<<(EDG + 1023) / 1024, 256, 0, stream>>>(grows, gcols, gvals, cursor, colval);
  kspmm<<<N_NODE / 4, 256, 0, stream>>>(starts, counts, colval, nemb, x1);
  kspmm<<<N_NODE / 4, 256, 0, stream>>>(starts, counts, colval, x1, x2);
  kcomb<<<N_NODE / 4, 256, 0, stream>>>(nemb, x1, x2, bI, emb_gnn);
  kgat<<<BB, 256, 0, stream>>>(emb_gnn, items, adjp, a0p, a1p, a2p, a3p, hgat);
  kseq<<<(BB * LL * EMB) / 256, 256, 0, stream>>>(emb_gnn, rev, alias, hgat, hseq);
  kprep_t<<<40, 256, 0, stream>>>(w1W, g1W, g2W, w1t2, glu1t, glu2t);
  kprep_pos<<<20, 256, 0, stream>>>(posE, w1W, w1b, posW);
  ksoft<<<BB, 256, 0, stream>>>(hseq, slen, maskp, posW, w1t2, glu1t, g1b, glu2t, w2p, sel);
  // hgat(x1) dead after kseq, hseq(x2) dead after ksoft -> safe to build bHi/bLo now
  kprepB<<<(N_NODE * 128) / 256, 256, 0, stream>>>(emb_gnn, bHi, bLo);
  ksess<<<BB, 128, 0, stream>>>(sadj, sel, y1);
  ksess<<<BB, 128, 0, stream>>>(sadj, y1, y2);
  ksesscomb<<<BB / 4, 256, 0, stream>>>(sel, y1, y2, aS, seqh);
  kprepA<<<(BB * 128) / 256, 256, 0, stream>>>(seqh, aHi, aLo);
  kscoresM<<<N_NODE / 32, 256, 0, stream>>>(aHi, aLo, bHi, bLo, outScores);
  klse<<<BB, 256, 0, stream>>>(outScores, tar, part);
  kfinal<<<1, 256, 0, stream>>>(part, outF);
}

// Round 6
// 553.115 us; speedup vs baseline: 1.0134x; 1.0134x over previous
//
#include <hip/hip_runtime.h>
#include <hip/hip_bf16.h>
#include <math.h>

#define N_NODE 40000
#define EMB 100
#define BB 512
#define LL 50
#define NI 50
#define EDG 800000
#define SCAN_BLOCKS 157  // ceil(40000/256)

typedef short s16x8 __attribute__((ext_vector_type(8)));   // 8 bf16 = 4 VGPRs
typedef float f32x4 __attribute__((ext_vector_type(4)));   // MFMA 16x16 accumulator

// ---------------- CSR build ----------------
__global__ void khist(const int* __restrict__ rows, int* __restrict__ counts) {
  int e = blockIdx.x * 256 + threadIdx.x;
  atomicAdd(&counts[rows[e]], 1);
}

// block-local exclusive scan (256 elems/block) + block sums
__global__ __launch_bounds__(256) void kscan1(const int* __restrict__ counts,
                                              int* __restrict__ scanout,
                                              int* __restrict__ blocksums, int n) {
  __shared__ int wsum[4];
  int tid = threadIdx.x;
  int i = blockIdx.x * 256 + tid;
  int v = (i < n) ? counts[i] : 0;
  int x = v;
  #pragma unroll
  for (int off = 1; off < 64; off <<= 1) {
    int t = __shfl_up(x, off, 64);
    if ((tid & 63) >= off) x += t;
  }
  int w = tid >> 6, lane = tid & 63;
  if (lane == 63) wsum[w] = x;
  __syncthreads();
  int woff = 0;
  #pragma unroll
  for (int k = 0; k < 4; ++k) woff += (k < w) ? wsum[k] : 0;
  int incl = x + woff;
  if (i < n) scanout[i] = incl - v;  // block-local exclusive
  if (tid == 255) blocksums[blockIdx.x] = incl;
}

// scan the block sums (one block, 256 threads >= 157)
__global__ __launch_bounds__(256) void kscan2(int* __restrict__ blocksums, int nb) {
  __shared__ int wsum[4];
  int tid = threadIdx.x;
  int v = (tid < nb) ? blocksums[tid] : 0;
  int x = v;
  #pragma unroll
  for (int off = 1; off < 64; off <<= 1) {
    int t = __shfl_up(x, off, 64);
    if ((tid & 63) >= off) x += t;
  }
  int w = tid >> 6, lane = tid & 63;
  if (lane == 63) wsum[w] = x;
  __syncthreads();
  int woff = 0;
  #pragma unroll
  for (int k = 0; k < 4; ++k) woff += (k < w) ? wsum[k] : 0;
  if (tid < nb) blocksums[tid] = x + woff - v;  // exclusive
}

// add block offsets, produce starts + cursor
__global__ __launch_bounds__(256) void kscan3(const int* __restrict__ scanout,
                                              const int* __restrict__ blocksums,
                                              int* __restrict__ starts,
                                              int* __restrict__ cursor, int n) {
  int i = blockIdx.x * 256 + threadIdx.x;
  if (i < n) {
    int s = scanout[i] + blocksums[blockIdx.x];
    starts[i] = s;
    cursor[i] = s;
  }
}

// fill: 4 edges/thread (4 independent atomic chains in flight), single int2
// scatter per edge (was 2x 4B to two arrays -> 2 dirtied lines; now 1).
__global__ __launch_bounds__(256) void kfill(const int* __restrict__ rows,
                                             const int* __restrict__ cols,
                                             const float* __restrict__ vals,
                                             int* __restrict__ cursor,
                                             int2* __restrict__ colval) {
  int e0 = (blockIdx.x * 256 + threadIdx.x) * 4;
  #pragma unroll
  for (int k = 0; k < 4; ++k) {
    int e = e0 + k;
    if (e < EDG) {
      int r = rows[e];
      int p = atomicAdd(&cursor[r], 1);
      int2 cv; cv.x = cols[e]; cv.y = __float_as_int(vals[e]);
      colval[p] = cv;
    }
  }
}

// ---------------- gather SpMM (wave per row, batched edges + 8x MLP) ----------
__global__ __launch_bounds__(256) void kspmm(const int* __restrict__ starts,
                                             const int* __restrict__ counts,
                                             const int2* __restrict__ colval,
                                             const float* __restrict__ x,
                                             float* __restrict__ out) {
  int row = blockIdx.x * 4 + (threadIdx.x >> 6);
  int lane = threadIdx.x & 63;
  int s = starts[row], cnt = counts[row];
  bool act = lane < 50;
  int d2 = (act ? lane : 49) * 2;      // clamped: inactive lanes re-read last pair
  float ax = 0.f, ay = 0.f;
  for (int base = 0; base < cnt; base += 64) {
    int nb = cnt - base; if (nb > 64) nb = 64;
    int cl = 0; float vl = 0.f;
    if (lane < nb) {
      int2 cv = colval[s + base + lane];
      cl = cv.x; vl = __int_as_float(cv.y);
    }
    int t = 0;
    for (; t + 8 <= nb; t += 8) {
      int c0 = __shfl(cl, t),     c1 = __shfl(cl, t + 1);
      int c2 = __shfl(cl, t + 2), c3 = __shfl(cl, t + 3);
      int c4 = __shfl(cl, t + 4), c5 = __shfl(cl, t + 5);
      int c6 = __shfl(cl, t + 6), c7 = __shfl(cl, t + 7);
      float v0 = __shfl(vl, t),     v1 = __shfl(vl, t + 1);
      float v2 = __shfl(vl, t + 2), v3 = __shfl(vl, t + 3);
      float v4 = __shfl(vl, t + 4), v5 = __shfl(vl, t + 5);
      float v6 = __shfl(vl, t + 6), v7 = __shfl(vl, t + 7);
      float2 g0 = *(const float2*)(x + (size_t)c0 * EMB + d2);
      float2 g1 = *(const float2*)(x + (size_t)c1 * EMB + d2);
      float2 g2 = *(const float2*)(x + (size_t)c2 * EMB + d2);
      float2 g3 = *(const float2*)(x + (size_t)c3 * EMB + d2);
      float2 g4 = *(const float2*)(x + (size_t)c4 * EMB + d2);
      float2 g5 = *(const float2*)(x + (size_t)c5 * EMB + d2);
      float2 g6 = *(const float2*)(x + (size_t)c6 * EMB + d2);
      float2 g7 = *(const float2*)(x + (size_t)c7 * EMB + d2);
      ax += v0 * g0.x; ay += v0 * g0.y;
      ax += v1 * g1.x; ay += v1 * g1.y;
      ax += v2 * g2.x; ay += v2 * g2.y;
      ax += v3 * g3.x; ay += v3 * g3.y;
      ax += v4 * g4.x; ay += v4 * g4.y;
      ax += v5 * g5.x; ay += v5 * g5.y;
      ax += v6 * g6.x; ay += v6 * g6.y;
      ax += v7 * g7.x; ay += v7 * g7.y;
    }
    for (; t + 4 <= nb; t += 4) {
      int c0 = __shfl(cl, t),     c1 = __shfl(cl, t + 1);
      int c2 = __shfl(cl, t + 2), c3 = __shfl(cl, t + 3);
      float v0 = __shfl(vl, t),     v1 = __shfl(vl, t + 1);
      float v2 = __shfl(vl, t + 2), v3 = __shfl(vl, t + 3);
      float2 g0 = *(const float2*)(x + (size_t)c0 * EMB + d2);
      float2 g1 = *(const float2*)(x + (size_t)c1 * EMB + d2);
      float2 g2 = *(const float2*)(x + (size_t)c2 * EMB + d2);
      float2 g3 = *(const float2*)(x + (size_t)c3 * EMB + d2);
      ax += v0 * g0.x; ay += v0 * g0.y;
      ax += v1 * g1.x; ay += v1 * g1.y;
      ax += v2 * g2.x; ay += v2 * g2.y;
      ax += v3 * g3.x; ay += v3 * g3.y;
    }
    for (; t < nb; ++t) {
      int c = __shfl(cl, t);
      float v = __shfl(vl, t);
      float2 g = *(const float2*)(x + (size_t)c * EMB + d2);
      ax += v * g.x; ay += v * g.y;
    }
  }
  if (act) {
    float2 o; o.x = ax; o.y = ay;
    *(float2*)(out + (size_t)row * EMB + d2) = o;
  }
}

// ---------------- l2norm-combine (item conv epilogue) ----------------
__global__ void kcomb(const float* __restrict__ x0, const float* __restrict__ x1,
                      const float* __restrict__ x2, const float* __restrict__ bI,
                      float* __restrict__ emb) {
  int n = blockIdx.x * 4 + (threadIdx.x >> 6);
  int lane = threadIdx.x & 63;
  int d0 = lane, d1 = lane + 64;
  bool h1 = d1 < EMB;
  size_t base = (size_t)n * EMB;
  float v00 = x0[base + d0], v01 = h1 ? x0[base + d1] : 0.f;
  float v10 = x1[base + d0], v11 = h1 ? x1[base + d1] : 0.f;
  float v20 = x2[base + d0], v21 = h1 ? x2[base + d1] : 0.f;
  float q0 = v00 * v00 + v01 * v01;
  float q1 = v10 * v10 + v11 * v11;
  float q2 = v20 * v20 + v21 * v21;
  #pragma unroll
  for (int off = 32; off; off >>= 1) {
    q0 += __shfl_xor(q0, off);
    q1 += __shfl_xor(q1, off);
    q2 += __shfl_xor(q2, off);
  }
  float r0 = 1.f / fmaxf(sqrtf(q0), 1e-12f);
  float r1 = 1.f / fmaxf(sqrtf(q1), 1e-12f);
  float r2 = 1.f / fmaxf(sqrtf(q2), 1e-12f);
  float b0 = bI[0], b1 = bI[1], b2 = bI[2];
  emb[base + d0] = b0 * v00 * r0 + b1 * v10 * r1 + b2 * v20 * r2;
  if (h1) emb[base + d1] = b0 * v01 * r0 + b1 * v11 * r1 + b2 * v21 * r2;
}

// ---------------- GAT v4: lane = output row, h-row in registers ----------------
__global__ __launch_bounds__(256) void kgat(
    const float* __restrict__ emb, const int* __restrict__ items,
    const int* __restrict__ adj,
    const float* __restrict__ a0p, const float* __restrict__ a1p,
    const float* __restrict__ a2p, const float* __restrict__ a3p,
    float* __restrict__ hgat) {
  __shared__ __align__(16) float hl[64 * 108];     // 27.6 KB, rows 50..63 zeroed
  __shared__ __align__(16) float as[4 * 100];      // 1.6 KB
  __shared__ float alpha_lds[64 * 51];             // 13.1 KB
  __shared__ float wred[4][2][64];                 // 2 KB
  int b = blockIdx.x;
  int tid = threadIdx.x;
  for (int idx = tid; idx < 400; idx += 256) {
    int k = idx / 100, d = idx % 100;
    const float* ap = (k == 0) ? a0p : (k == 1) ? a1p : (k == 2) ? a2p : a3p;
    as[idx] = ap[d];
  }
  for (int idx = tid; idx < 64 * 50; idx += 256) {
    int i = idx / 50, d2 = (idx % 50) * 2;
    float2 v; v.x = 0.f; v.y = 0.f;
    if (i < NI) {
      int node = items[b * NI + i];
      if (node != 0) v = *(const float2*)(emb + (size_t)(node - 1) * EMB + d2);
    }
    *(float2*)&hl[i * 108 + d2] = v;
  }
  __syncthreads();
  int w = tid >> 6, lane = tid & 63;
  int j0 = w * 13;
  int nj = 50 - j0; if (nj > 13) nj = 13;          // 13,13,13,11

  // my h-row into registers (lanes >=50 read zeroed rows -> e = 0, harmless)
  float4 hreg[25];
  #pragma unroll
  for (int q = 0; q < 25; ++q) hreg[q] = *(const float4*)&hl[lane * 108 + q * 4];

  // adj row slice (clamp lane to stay in-bounds for lanes 50..63)
  int al_lane = (lane < NI) ? lane : NI - 1;
  const int* adjrow = adj + (size_t)b * (NI * NI) + al_lane * NI + j0;
  int adjv[13];
  #pragma unroll
  for (int t = 0; t < 13; ++t) adjv[t] = (t < nj) ? adjrow[t] : 0;

  // ---- scores: e[jj] for my row vs j0+jj ----
  float e[13];
  #pragma unroll
  for (int jj = 0; jj < 13; ++jj) {
    float acc = 0.f;
    if (jj < nj) {
      int j = j0 + jj;
      int k = adjv[jj] - 1; k = (k < 0) ? 0 : (k > 3) ? 3 : k;
      const float* aw = &as[k * 100];
      #pragma unroll
      for (int q = 0; q < 25; ++q) {
        float4 hj = *(const float4*)&hl[j * 108 + q * 4];   // uniform broadcast
        float4 a4 = *(const float4*)(aw + q * 4);           // <=4 distinct addrs
        float4 hm = hreg[q];
        acc += hm.x * hj.x * a4.x + hm.y * hj.y * a4.y
             + hm.z * hj.z * a4.z + hm.w * hj.w * a4.w;
      }
      acc = (acc >= 0.f) ? acc : 0.2f * acc;     // leakyrelu
      acc = (adjv[jj] == 0) ? -9e15f : acc;      // mask (matches reference)
    } else {
      acc = -INFINITY;                           // excluded from max/sum
    }
    e[jj] = acc;
  }

  // ---- softmax across waves (per-lane row-local) ----
  float mloc = -INFINITY;
  #pragma unroll
  for (int jj = 0; jj < 13; ++jj) if (jj < nj) mloc = fmaxf(mloc, e[jj]);
  wred[w][0][lane] = mloc;
  __syncthreads();
  float m = fmaxf(fmaxf(wred[0][0][lane], wred[1][0][lane]),
                  fmaxf(wred[2][0][lane], wred[3][0][lane]));
  float sloc = 0.f;
  #pragma unroll
  for (int jj = 0; jj < 13; ++jj) if (jj < nj) {
    e[jj] = expf(e[jj] - m);
    sloc += e[jj];
  }
  wred[w][1][lane] = sloc;
  __syncthreads();
  float s = (wred[0][1][lane] + wred[1][1][lane]) +
            (wred[2][1][lane] + wred[3][1][lane]);
  float inv = 1.f / s;
  #pragma unroll
  for (int jj = 0; jj < 13; ++jj) if (jj < nj)
    alpha_lds[lane * 51 + j0 + jj] = e[jj] * inv;
  __syncthreads();

  // ---- PV: out[i][d] = sum_j alpha[i][j] * h[j][d]; wave w owns quads w+4t ----
  int nq = (w == 0) ? 7 : 6;
  float4 outq[7];
  #pragma unroll
  for (int t = 0; t < 7; ++t) outq[t] = make_float4(0.f, 0.f, 0.f, 0.f);
  for (int j = 0; j < NI; ++j) {
    float aj = alpha_lds[lane * 51 + j];        // stride 51 -> conflict-free
    #pragma unroll
    for (int t = 0; t < 7; ++t) {
      if (t < nq) {
        int q = w + 4 * t;
        float4 hv = *(const float4*)&hl[j * 108 + q * 4];   // uniform broadcast
        outq[t].x += aj * hv.x; outq[t].y += aj * hv.y;
        outq[t].z += aj * hv.z; outq[t].w += aj * hv.w;
      }
    }
  }
  if (lane < NI) {
    #pragma unroll
    for (int t = 0; t < 7; ++t) {
      if (t < nq) {
        int q = w + 4 * t;
        *(float4*)&hgat[((size_t)b * NI + lane) * EMB + q * 4] = outq[t];
      }
    }
  }
}

// ---------------- get_seq mix ----------------
__global__ void kseq(const float* __restrict__ emb, const int* __restrict__ rev,
                     const int* __restrict__ alias, const float* __restrict__ hgat,
                     float* __restrict__ hseq) {
  int idx = blockIdx.x * 256 + threadIdx.x;  // 2,560,000 exact
  int b = idx / 5000, r = idx % 5000, l = r / 100, d = r % 100;
  int node = rev[b * LL + l];
  float sh = (node == 0) ? 0.f : emb[(size_t)(node - 1) * EMB + d];
  int a = alias[b * LL + l];
  float shh = hgat[((size_t)b * NI + a) * EMB + d];
  hseq[idx] = 0.2f * sh + 0.8f * shh;
}

// ---------------- weight prep: transposes + pos@W1a ----------------
__global__ void kprep_t(const float* __restrict__ w1W, const float* __restrict__ g1W,
                        const float* __restrict__ g2W, float* __restrict__ w1t2,
                        float* __restrict__ g1t, float* __restrict__ g2t) {
  int idx = blockIdx.x * 256 + threadIdx.x;
  if (idx >= 10000) return;
  int c = idx / 100, o = idx % 100;
  w1t2[c * 100 + o] = w1W[o * 200 + 100 + c];
  g1t[c * 100 + o] = g1W[o * 100 + c];
  g2t[c * 100 + o] = g2W[o * 100 + c];
}

__global__ void kprep_pos(const float* __restrict__ posE, const float* __restrict__ w1W,
                          const float* __restrict__ w1b, float* __restrict__ posW) {
  int idx = blockIdx.x * 256 + threadIdx.x;
  if (idx >= 5000) return;
  int l = idx / 100, o = idx % 100;
  float acc = w1b[o];
  for (int c = 0; c < 100; ++c) acc += posE[l * 100 + c] * w1W[o * 200 + c];
  posW[idx] = acc;
}

// ---------------- soft attention (block per batch, register-tiled) ----------------
__global__ __launch_bounds__(256) void ksoft(
    const float* __restrict__ hseqG, const float* __restrict__ slenp,
    const int* __restrict__ maskp,
    const float* __restrict__ posW, const float* __restrict__ w1t2,
    const float* __restrict__ glu1t, const float* __restrict__ glu1b,
    const float* __restrict__ glu2t, const float* __restrict__ w2,
    float* __restrict__ sel) {
  __shared__ float hq[LL * 101];       // 20.2 KB
  __shared__ float nh[LL * 100];       // 20 KB
  __shared__ float red[25 * 52];       // 5.2 KB  (red[og][l])
  __shared__ float hs_s[100];
  __shared__ float g_s[100];
  __shared__ float beta_s[LL];
  int b = blockIdx.x, tid = threadIdx.x;
  for (int idx = tid; idx < LL * 100; idx += 256) {
    int l = idx / 100, d = idx % 100;
    hq[l * 101 + d] = hseqG[((size_t)b * LL + l) * 100 + d];
  }
  __syncthreads();
  if (tid < 100) {
    float s = 0.f;
    for (int l = 0; l < LL; ++l) s += hq[l * 101 + tid];
    hs_s[tid] = s / slenp[b];
  }
  __syncthreads();
  if (tid < 100) {
    float acc = 0.f;
    for (int c = 0; c < 100; ++c) acc += hs_s[c] * glu2t[c * 100 + tid];
    g_s[tid] = acc;
  }
  // ---- phase B: nh = tanh(hq @ w1t2 + posW) ----
  int lg = tid / 25, og = tid % 25;    // valid when tid < 250
  if (tid < 250) {
    float acc[5][4];
    #pragma unroll
    for (int j = 0; j < 5; ++j) {
      float4 p = *(const float4*)&posW[(lg * 5 + j) * 100 + og * 4];
      acc[j][0] = p.x; acc[j][1] = p.y; acc[j][2] = p.z; acc[j][3] = p.w;
    }
    for (int c = 0; c < 100; ++c) {
      float4 wv = *(const float4*)&w1t2[c * 100 + og * 4];
      float hv[5];
      #pragma unroll
      for (int j = 0; j < 5; ++j) hv[j] = hq[(lg * 5 + j) * 101 + c];
      #pragma unroll
      for (int j = 0; j < 5; ++j) {
        acc[j][0] += hv[j] * wv.x;
        acc[j][1] += hv[j] * wv.y;
        acc[j][2] += hv[j] * wv.z;
        acc[j][3] += hv[j] * wv.w;
      }
    }
    #pragma unroll
    for (int j = 0; j < 5; ++j) {
      float4 t;
      t.x = tanhf(acc[j][0]); t.y = tanhf(acc[j][1]);
      t.z = tanhf(acc[j][2]); t.w = tanhf(acc[j][3]);
      *(float4*)&nh[(lg * 5 + j) * 100 + og * 4] = t;
    }
  }
  __syncthreads();  // nh + g_s visible
  // ---- phase C: val = sigmoid(nh @ glu1t + g + b) * w2; row-sum -> red ----
  if (tid < 250) {
    float4 gb = *(const float4*)&glu1b[og * 4];
    float4 gg = *(const float4*)&g_s[og * 4];
    float base0 = gg.x + gb.x, base1 = gg.y + gb.y, base2 = gg.z + gb.z, base3 = gg.w + gb.w;
    float acc[5][4];
    #pragma unroll
    for (int j = 0; j < 5; ++j) {
      acc[j][0] = base0; acc[j][1] = base1; acc[j][2] = base2; acc[j][3] = base3;
    }
    for (int c = 0; c < 100; ++c) {
      float4 wv = *(const float4*)&glu1t[c * 100 + og * 4];
      float hv[5];
      #pragma unroll
      for (int j = 0; j < 5; ++j) hv[j] = nh[(lg * 5 + j) * 100 + c];
      #pragma unroll
      for (int j = 0; j < 5; ++j) {
        acc[j][0] += hv[j] * wv.x;
        acc[j][1] += hv[j] * wv.y;
        acc[j][2] += hv[j] * wv.z;
        acc[j][3] += hv[j] * wv.w;
      }
    }
    float4 w2v = *(const float4*)&w2[og * 4];
    #pragma unroll
    for (int j = 0; j < 5; ++j) {
      float s0 = w2v.x / (1.f + expf(-acc[j][0]));
      float s1 = w2v.y / (1.f + expf(-acc[j][1]));
      float s2 = w2v.z / (1.f + expf(-acc[j][2]));
      float s3 = w2v.w / (1.f + expf(-acc[j][3]));
      red[og * 52 + lg * 5 + j] = (s0 + s1) + (s2 + s3);
    }
  }
  __syncthreads();
  if (tid < LL) {
    float s = 0.f;
    for (int og2 = 0; og2 < 25; ++og2) s += red[og2 * 52 + tid];
    beta_s[tid] = s * (float)maskp[b * LL + tid];
  }
  __syncthreads();
  if (tid < 100) {
    float acc = 0.f;
    for (int l = 0; l < LL; ++l) acc += beta_s[l] * hq[l * 101 + tid];
    sel[(size_t)b * 100 + tid] = acc;
  }
}

// ---------------- session conv: dense [512,512] @ [512,100] ----------------
__global__ void ksess(const float* __restrict__ adjS, const float* __restrict__ x,
                      float* __restrict__ out) {
  int b = blockIdx.x, d = threadIdx.x;
  if (d >= 100) return;
  const float* ar = adjS + (size_t)b * BB;
  float a0 = 0.f, a1 = 0.f, a2 = 0.f, a3 = 0.f;
  for (int j = 0; j < BB; j += 4) {
    a0 += ar[j]     * x[(j)     * 100 + d];
    a1 += ar[j + 1] * x[(j + 1) * 100 + d];
    a2 += ar[j + 2] * x[(j + 2) * 100 + d];
    a3 += ar[j + 3] * x[(j + 3) * 100 + d];
  }
  out[(size_t)b * 100 + d] = (a0 + a1) + (a2 + a3);
}

__global__ void ksesscomb(const float* __restrict__ x0, const float* __restrict__ x1,
                          const float* __restrict__ x2, const float* __restrict__ aS,
                          float* __restrict__ out) {
  int b = blockIdx.x * 4 + (threadIdx.x >> 6);
  int lane = threadIdx.x & 63;
  int d0 = lane, d1 = lane + 64;
  bool h1 = d1 < EMB;
  size_t base = (size_t)b * EMB;
  float v00 = x0[base + d0], v01 = h1 ? x0[base + d1] : 0.f;
  float v10 = x1[base + d0], v11 = h1 ? x1[base + d1] : 0.f;
  float v20 = x2[base + d0], v21 = h1 ? x2[base + d1] : 0.f;
  float q0 = v00 * v00 + v01 * v01;
  float q1 = v10 * v10 + v11 * v11;
  float q2 = v20 * v20 + v21 * v21;
  #pragma unroll
  for (int off = 32; off; off >>= 1) {
    q0 += __shfl_xor(q0, off);
    q1 += __shfl_xor(q1, off);
    q2 += __shfl_xor(q2, off);
  }
  float r0 = 1.f / fmaxf(sqrtf(q0), 1e-12f);
  float r1 = 1.f / fmaxf(sqrtf(q1), 1e-12f);
  float r2 = 1.f / fmaxf(sqrtf(q2), 1e-12f);
  float b0 = aS[0], b1 = aS[1], b2 = aS[2];
  // seq_h = sel1+sel2 = 2 * session_conv output
  out[base + d0] = 2.f * (b0 * v00 * r0 + b1 * v10 * r1 + b2 * v20 * r2);
  if (h1) out[base + d1] = 2.f * (b0 * v01 * r0 + b1 * v11 * r1 + b2 * v21 * r2);
}

// ---------------- bf16 hi/lo split prep ----------------
// B = 2*emb_gnn -> [40000][128] padded; A = seqh -> [512][128] padded
__global__ void kprepB(const float* __restrict__ emb, unsigned short* __restrict__ bHi,
                       unsigned short* __restrict__ bLo) {
  int idx = blockIdx.x * 256 + threadIdx.x;  // 5,120,000 exact
  int n = idx >> 7, k = idx & 127;
  float v = (k < EMB) ? 2.f * emb[(size_t)n * EMB + k] : 0.f;
  __hip_bfloat16 h = __float2bfloat16(v);
  float rem = v - __bfloat162float(h);
  __hip_bfloat16 l = __float2bfloat16(rem);
  bHi[idx] = *reinterpret_cast<unsigned short*>(&h);
  bLo[idx] = *reinterpret_cast<unsigned short*>(&l);
}

__global__ void kprepA(const float* __restrict__ seqh, unsigned short* __restrict__ aHi,
                       unsigned short* __restrict__ aLo) {
  int idx = blockIdx.x * 256 + threadIdx.x;  // 65,536 exact
  int n = idx >> 7, k = idx & 127;
  float v = (k < EMB) ? seqh[(size_t)n * EMB + k] : 0.f;
  __hip_bfloat16 h = __float2bfloat16(v);
  float rem = v - __bfloat162float(h);
  __hip_bfloat16 l = __float2bfloat16(rem);
  aHi[idx] = *reinterpret_cast<unsigned short*>(&h);
  aLo[idx] = *reinterpret_cast<unsigned short*>(&l);
}

// ---------------- scores GEMM v3: 64x64 tile, 2 b-steps per block ----------------
// v1 (64x64, grid 625x8): 50 us, staging-dominated (B staged 8x = 170 MB).
// v2 (32-col, 8-step b-loop): REGRESSED to 58 us -- half-line writes inflated
// WRITE 90->100 MB, and per-step A-load -> MFMA serial chain had no overlap.
// v3: v1 structure, but each block does TWO 64-row b-steps (B staged 4x = 85 MB)
// with ALL A fragments loaded up-front (64 VGPR, static idx) -- A-latency hides
// under B staging; 64-col stores keep full-sector write pattern.
// Grid (4, 625): x = b-group (adjacent dispatch shares B tile in L2/L3).
__global__ __launch_bounds__(256) void kscoresM(
    const unsigned short* __restrict__ aHi, const unsigned short* __restrict__ aLo,
    const unsigned short* __restrict__ bHi, const unsigned short* __restrict__ bLo,
    float* __restrict__ outS) {
  __shared__ __align__(16) unsigned short Bh[64 * 136];  // 136 = 128 + 8 pad
  __shared__ __align__(16) unsigned short Bl[64 * 136];
  int tid = threadIdx.x;
  int n0 = blockIdx.y * 64;
  int bbase = blockIdx.x * 128;          // 2 b-steps of 64 rows
  int w = tid >> 6, lane = tid & 63;
  int ln = lane & 15, quad = lane >> 4;

  // A fragments for BOTH b-steps, loaded up-front (L2-hot, 256 KB total set)
  const unsigned short* aRowH0 = aHi + (size_t)(bbase + w * 16 + ln) * 128 + quad * 8;
  const unsigned short* aRowL0 = aLo + (size_t)(bbase + w * 16 + ln) * 128 + quad * 8;
  const unsigned short* aRowH1 = aRowH0 + 64 * 128;
  const unsigned short* aRowL1 = aRowL0 + 64 * 128;
  s16x8 ah0[4], al0[4], ah1[4], al1[4];
  #pragma unroll
  for (int s = 0; s < 4; ++s) {
    ah0[s] = *(const s16x8*)(aRowH0 + s * 32);
    al0[s] = *(const s16x8*)(aRowL0 + s * 32);
    ah1[s] = *(const s16x8*)(aRowH1 + s * 32);
    al1[s] = *(const s16x8*)(aRowL1 + s * 32);
  }

  // stage B tile (64 rows x 128 k, hi+lo) into LDS -- once for both b-steps
  #pragma unroll
  for (int it = 0; it < 4; ++it) {
    int seg = tid + it * 256;      // 0..1023
    int r = seg >> 4, q = seg & 15;
    *(s16x8*)&Bh[r * 136 + q * 8] = *(const s16x8*)&bHi[(size_t)(n0 + r) * 128 + q * 8];
    *(s16x8*)&Bl[r * 136 + q * 8] = *(const s16x8*)&bLo[(size_t)(n0 + r) * 128 + q * 8];
  }
  __syncthreads();

  // ---- b-step 0 ----
  f32x4 acc[4];
  #pragma unroll
  for (int t = 0; t < 4; ++t) acc[t] = (f32x4){0.f, 0.f, 0.f, 0.f};
  #pragma unroll
  for (int s = 0; s < 4; ++s) {
    #pragma unroll
    for (int t = 0; t < 4; ++t) {
      s16x8 bh = *(const s16x8*)&Bh[(t * 16 + ln) * 136 + s * 32 + quad * 8];
      s16x8 bl = *(const s16x8*)&Bl[(t * 16 + ln) * 136 + s * 32 + quad * 8];
      acc[t] = __builtin_amdgcn_mfma_f32_16x16x32_bf16(ah0[s], bh, acc[t], 0, 0, 0);
      acc[t] = __builtin_amdgcn_mfma_f32_16x16x32_bf16(al0[s], bh, acc[t], 0, 0, 0);
      acc[t] = __builtin_amdgcn_mfma_f32_16x16x32_bf16(ah0[s], bl, acc[t], 0, 0, 0);
    }
  }
  {
    int brow = bbase + w * 16 + quad * 4;
    #pragma unroll
    for (int t = 0; t < 4; ++t) {
      int ncol = n0 + t * 16 + ln;
      #pragma unroll
      for (int r = 0; r < 4; ++r) {
        outS[(size_t)(brow + r) * N_NODE + ncol] = acc[t][r];
      }
    }
  }

  // ---- b-step 1 ----
  #pragma unroll
  for (int t = 0; t < 4; ++t) acc[t] = (f32x4){0.f, 0.f, 0.f, 0.f};
  #pragma unroll
  for (int s = 0; s < 4; ++s) {
    #pragma unroll
    for (int t = 0; t < 4; ++t) {
      s16x8 bh = *(const s16x8*)&Bh[(t * 16 + ln) * 136 + s * 32 + quad * 8];
      s16x8 bl = *(const s16x8*)&Bl[(t * 16 + ln) * 136 + s * 32 + quad * 8];
      acc[t] = __builtin_amdgcn_mfma_f32_16x16x32_bf16(ah1[s], bh, acc[t], 0, 0, 0);
      acc[t] = __builtin_amdgcn_mfma_f32_16x16x32_bf16(al1[s], bh, acc[t], 0, 0, 0);
      acc[t] = __builtin_amdgcn_mfma_f32_16x16x32_bf16(ah1[s], bl, acc[t], 0, 0, 0);
    }
  }
  {
    int brow = bbase + 64 + w * 16 + quad * 4;
    #pragma unroll
    for (int t = 0; t < 4; ++t) {
      int ncol = n0 + t * 16 + ln;
      #pragma unroll
      for (int r = 0; r < 4; ++r) {
        outS[(size_t)(brow + r) * N_NODE + ncol] = acc[t][r];
      }
    }
  }
}

// ---------------- per-row logsumexp + target score ----------------
__global__ __launch_bounds__(256) void klse(const float* __restrict__ outS,
                                            const int* __restrict__ tar,
                                            float* __restrict__ part) {
  __shared__ float ms[256], ss[256];
  int b = blockIdx.x, tid = threadIdx.x;
  const float2* sp = (const float2*)(outS + (size_t)b * N_NODE);
  float m = -INFINITY, s = 0.f;
  for (int i = tid; i < N_NODE / 2; i += 256) {
    float2 v = sp[i];
    float mx = fmaxf(v.x, v.y);
    float add = expf(v.x - mx) + expf(v.y - mx);
    if (mx > m) { s = s * expf(m - mx) + add; m = mx; }
    else s += add * expf(mx - m);
  }
  ms[tid] = m; ss[tid] = s;
  __syncthreads();
  for (int st = 128; st; st >>= 1) {
    if (tid < st) {
      float m2 = ms[tid + st], s2 = ss[tid + st];
      float M = fmaxf(ms[tid], m2);
      ss[tid] = ss[tid] * expf(ms[tid] - M) + s2 * expf(m2 - M);
      ms[tid] = M;
    }
    __syncthreads();
  }
  if (tid == 0) {
    float tsc = outS[(size_t)b * N_NODE + tar[b]];
    part[b] = tsc - (ms[0] + logf(ss[0]));
  }
}

__global__ void kfinal(const float* __restrict__ part, float* __restrict__ out) {
  __shared__ float red[256];
  int tid = threadIdx.x;
  red[tid] = part[tid] + part[tid + 256];
  __syncthreads();
  for (int st = 128; st; st >>= 1) {
    if (tid < st) red[tid] += red[tid + st];
    __syncthreads();
  }
  if (tid == 0) {
    out[0] = 0.f;                        // con_loss
    out[1] = -red[0] / (float)BB;        // loss
  }
}

extern "C" void kernel_launch(void* const* d_in, const int* in_sizes, int n_in,
                              void* d_out, int out_size, void* d_ws, size_t ws_size,
                              hipStream_t stream) {
  const int* tar    = (const int*)d_in[0];
  const int* rev    = (const int*)d_in[1];
  const int* maskp  = (const int*)d_in[2];
  const float* slen = (const float*)d_in[3];
  const float* sadj = (const float*)d_in[4];
  const int* items  = (const int*)d_in[6];
  const int* adjp   = (const int*)d_in[7];
  const int* alias  = (const int*)d_in[8];
  const int* grows  = (const int*)d_in[9];
  const int* gcols  = (const int*)d_in[10];
  const float* gvals = (const float*)d_in[11];
  const float* nemb = (const float*)d_in[12];
  const float* bI   = (const float*)d_in[13];
  const float* aS   = (const float*)d_in[14];
  const float* a0p  = (const float*)d_in[15];
  const float* a1p  = (const float*)d_in[16];
  const float* a2p  = (const float*)d_in[17];
  const float* a3p  = (const float*)d_in[18];
  const float* w1W  = (const float*)d_in[19];
  const float* w1b  = (const float*)d_in[20];
  const float* w2p  = (const float*)d_in[21];
  const float* g1W  = (const float*)d_in[22];
  const float* g1b  = (const float*)d_in[23];
  const float* g2W  = (const float*)d_in[24];
  const float* posE = (const float*)d_in[25];

  float* W = (float*)d_ws;
  size_t o = 0;
  float* emb_gnn = W + o; o += (size_t)N_NODE * EMB;   // 4,000,000
  float* x1      = W + o; o += (size_t)N_NODE * EMB;   // reused: hgat, then bHi
  float* x2      = W + o; o += (size_t)N_NODE * EMB;   // reused: hseq, then bLo
  float* sel     = W + o; o += (size_t)BB * EMB;
  float* y1      = W + o; o += (size_t)BB * EMB;
  float* y2      = W + o; o += (size_t)BB * EMB;
  float* seqh    = W + o; o += (size_t)BB * EMB;
  float* posW    = W + o; o += 5120;
  float* w1t2    = W + o; o += 10000;
  float* glu1t   = W + o; o += 10000;
  float* glu2t   = W + o; o += 10000;
  int2* colval   = (int2*)(W + o); o += (size_t)2 * EDG;  // merged {col,val}
  float* part    = W + o; o += 512;
  int* counts = (int*)(W + o); o += N_NODE;
  int* starts = (int*)(W + o); o += N_NODE;
  int* cursor = (int*)(W + o); o += N_NODE;
  int* scantmp = (int*)(W + o); o += N_NODE;
  int* blocksums = (int*)(W + o); o += 256;
  unsigned short* aHi = (unsigned short*)(W + o); o += 32768;  // 512*128 bf16 = 32768 floats/2
  unsigned short* aLo = (unsigned short*)(W + o); o += 32768;
  // hgat/hseq alias x1/x2 (dead after kcomb); bHi/bLo alias x1/x2 (hgat dead after
  // kseq, hseq dead after ksoft; each needs 2.56M floats of the 4M region)
  float* hgat = x1;
  float* hseq = x2;
  unsigned short* bHi = (unsigned short*)x1;   // 5.12M u16 = 2.56M floats <= 4M
  unsigned short* bLo = (unsigned short*)x2;

  float* outF = (float*)d_out;
  float* outScores = outF + 2;

  hipMemsetAsync(counts, 0, N_NODE * sizeof(int), stream);
  khist<<<EDG / 256, 256, 0, stream>>>(grows, counts);
  kscan1<<<SCAN_BLOCKS, 256, 0, stream>>>(counts, scantmp, blocksums, N_NODE);
  kscan2<<<1, 256, 0, stream>>>(blocksums, SCAN_BLOCKS);
  kscan3<<<SCAN_BLOCKS, 256, 0, stream>>>(scantmp, blocksums, starts, cursor, N_NODE);
  kfill<<<(EDG + 1023) / 1024, 256, 0, stream>>>(grows, gcols, gvals, cursor, colval);
  kspmm<<<N_NODE / 4, 256, 0, stream>>>(starts, counts, colval, nemb, x1);
  kspmm<<<N_NODE / 4, 256, 0, stream>>>(starts, counts, colval, x1, x2);
  kcomb<<<N_NODE / 4, 256, 0, stream>>>(nemb, x1, x2, bI, emb_gnn);
  kgat<<<BB, 256, 0, stream>>>(emb_gnn, items, adjp, a0p, a1p, a2p, a3p, hgat);
  kseq<<<(BB * LL * EMB) / 256, 256, 0, stream>>>(emb_gnn, rev, alias, hgat, hseq);
  kprep_t<<<40, 256, 0, stream>>>(w1W, g1W, g2W, w1t2, glu1t, glu2t);
  kprep_pos<<<20, 256, 0, stream>>>(posE, w1W, w1b, posW);
  ksoft<<<BB, 256, 0, stream>>>(hseq, slen, maskp, posW, w1t2, glu1t, g1b, glu2t, w2p, sel);
  // hgat(x1) dead after kseq, hseq(x2) dead after ksoft -> safe to build bHi/bLo now
  kprepB<<<(N_NODE * 128) / 256, 256, 0, stream>>>(emb_gnn, bHi, bLo);
  ksess<<<BB, 128, 0, stream>>>(sadj, sel, y1);
  ksess<<<BB, 128, 0, stream>>>(sadj, y1, y2);
  ksesscomb<<<BB / 4, 256, 0, stream>>>(sel, y1, y2, aS, seqh);
  kprepA<<<(BB * 128) / 256, 256, 0, stream>>>(seqh, aHi, aLo);
  kscoresM<<<dim3(4, N_NODE / 64), 256, 0, stream>>>(aHi, aLo, bHi, bLo, outScores);
  klse<<<BB, 256, 0, stream>>>(outScores, tar, part);
  kfinal<<<1, 256, 0, stream>>>(part, outF);
}

// Round 7
// 540.508 us; speedup vs baseline: 1.0370x; 1.0233x over previous
//
#include <hip/hip_runtime.h>
#include <hip/hip_bf16.h>
#include <math.h>

#define N_NODE 40000
#define EMB 100
#define BB 512
#define LL 50
#define NI 50
#define EDG 800000
#define SCAN_BLOCKS 157  // ceil(40000/256)

typedef short s16x8 __attribute__((ext_vector_type(8)));   // 8 bf16 = 4 VGPRs
typedef float f32x4 __attribute__((ext_vector_type(4)));   // MFMA 16x16 accumulator

// ---------------- CSR build ----------------
__global__ void khist(const int* __restrict__ rows, int* __restrict__ counts) {
  int e = blockIdx.x * 256 + threadIdx.x;
  atomicAdd(&counts[rows[e]], 1);
}

// block-local exclusive scan (256 elems/block) + block sums
__global__ __launch_bounds__(256) void kscan1(const int* __restrict__ counts,
                                              int* __restrict__ scanout,
                                              int* __restrict__ blocksums, int n) {
  __shared__ int wsum[4];
  int tid = threadIdx.x;
  int i = blockIdx.x * 256 + tid;
  int v = (i < n) ? counts[i] : 0;
  int x = v;
  #pragma unroll
  for (int off = 1; off < 64; off <<= 1) {
    int t = __shfl_up(x, off, 64);
    if ((tid & 63) >= off) x += t;
  }
  int w = tid >> 6, lane = tid & 63;
  if (lane == 63) wsum[w] = x;
  __syncthreads();
  int woff = 0;
  #pragma unroll
  for (int k = 0; k < 4; ++k) woff += (k < w) ? wsum[k] : 0;
  int incl = x + woff;
  if (i < n) scanout[i] = incl - v;  // block-local exclusive
  if (tid == 255) blocksums[blockIdx.x] = incl;
}

// scan the block sums (one block, 256 threads >= 157)
__global__ __launch_bounds__(256) void kscan2(int* __restrict__ blocksums, int nb) {
  __shared__ int wsum[4];
  int tid = threadIdx.x;
  int v = (tid < nb) ? blocksums[tid] : 0;
  int x = v;
  #pragma unroll
  for (int off = 1; off < 64; off <<= 1) {
    int t = __shfl_up(x, off, 64);
    if ((tid & 63) >= off) x += t;
  }
  int w = tid >> 6, lane = tid & 63;
  if (lane == 63) wsum[w] = x;
  __syncthreads();
  int woff = 0;
  #pragma unroll
  for (int k = 0; k < 4; ++k) woff += (k < w) ? wsum[k] : 0;
  if (tid < nb) blocksums[tid] = x + woff - v;  // exclusive
}

// add block offsets, produce starts + cursor
__global__ __launch_bounds__(256) void kscan3(const int* __restrict__ scanout,
                                              const int* __restrict__ blocksums,
                                              int* __restrict__ starts,
                                              int* __restrict__ cursor, int n) {
  int i = blockIdx.x * 256 + threadIdx.x;
  if (i < n) {
    int s = scanout[i] + blocksums[blockIdx.x];
    starts[i] = s;
    cursor[i] = s;
  }
}

// fill v3: XCD-partitioned scatter.  v2's WRITE_SIZE was 51 MB = 800K x 64 B --
// every 8B scatter wrote back a full line because a row's 8 positions are
// written from all 8 non-coherent per-XCD L2s (dirty-line duplication).
// Now: bid%8 = XCD (default round-robin dispatch); block with q = bid&7 handles
// ONLY rows [5000q, 5000q+5000).  Each partition's contiguous colval region
// (~800 KB) + cursor slice (20 KB) is written by ONE XCD -> lines accumulate
// all 8 writes in that L2, single writeback.  Cost: 8x re-read of rows[]
// (~70 MB coalesced reads ~ 14 us) -- cheap vs the 40 us scatter penalty.
__global__ __launch_bounds__(256) void kfill(const int* __restrict__ rows,
                                             const int* __restrict__ cols,
                                             const float* __restrict__ vals,
                                             int* __restrict__ cursor,
                                             int2* __restrict__ colval) {
  int q = blockIdx.x & 7;                 // partition == XCD (bid%8 round-robin)
  int chunk = blockIdx.x >> 3;
  int e0 = (chunk * 256 + threadIdx.x) * 4;
  int rlo = q * 5000, rhi = rlo + 5000;
  if (e0 + 3 < EDG) {
    int4 r4 = *(const int4*)(rows + e0);
    int rr0 = r4.x, rr1 = r4.y, rr2 = r4.z, rr3 = r4.w;
    if (rr0 >= rlo && rr0 < rhi) {
      int p = atomicAdd(&cursor[rr0], 1);
      int2 cv; cv.x = cols[e0];     cv.y = __float_as_int(vals[e0]);
      colval[p] = cv;
    }
    if (rr1 >= rlo && rr1 < rhi) {
      int p = atomicAdd(&cursor[rr1], 1);
      int2 cv; cv.x = cols[e0 + 1]; cv.y = __float_as_int(vals[e0 + 1]);
      colval[p] = cv;
    }
    if (rr2 >= rlo && rr2 < rhi) {
      int p = atomicAdd(&cursor[rr2], 1);
      int2 cv; cv.x = cols[e0 + 2]; cv.y = __float_as_int(vals[e0 + 2]);
      colval[p] = cv;
    }
    if (rr3 >= rlo && rr3 < rhi) {
      int p = atomicAdd(&cursor[rr3], 1);
      int2 cv; cv.x = cols[e0 + 3]; cv.y = __float_as_int(vals[e0 + 3]);
      colval[p] = cv;
    }
  } else {
    for (int k = 0; k < 4; ++k) {
      int e = e0 + k;
      if (e < EDG) {
        int r = rows[e];
        if (r >= rlo && r < rhi) {
          int p = atomicAdd(&cursor[r], 1);
          int2 cv; cv.x = cols[e]; cv.y = __float_as_int(vals[e]);
          colval[p] = cv;
        }
      }
    }
  }
}

// ---------------- gather SpMM (wave per row, batched edges + 8x MLP) ----------
__global__ __launch_bounds__(256) void kspmm(const int* __restrict__ starts,
                                             const int* __restrict__ counts,
                                             const int2* __restrict__ colval,
                                             const float* __restrict__ x,
                                             float* __restrict__ out) {
  int row = blockIdx.x * 4 + (threadIdx.x >> 6);
  int lane = threadIdx.x & 63;
  int s = starts[row], cnt = counts[row];
  bool act = lane < 50;
  int d2 = (act ? lane : 49) * 2;      // clamped: inactive lanes re-read last pair
  float ax = 0.f, ay = 0.f;
  for (int base = 0; base < cnt; base += 64) {
    int nb = cnt - base; if (nb > 64) nb = 64;
    int cl = 0; float vl = 0.f;
    if (lane < nb) {
      int2 cv = colval[s + base + lane];
      cl = cv.x; vl = __int_as_float(cv.y);
    }
    int t = 0;
    for (; t + 8 <= nb; t += 8) {
      int c0 = __shfl(cl, t),     c1 = __shfl(cl, t + 1);
      int c2 = __shfl(cl, t + 2), c3 = __shfl(cl, t + 3);
      int c4 = __shfl(cl, t + 4), c5 = __shfl(cl, t + 5);
      int c6 = __shfl(cl, t + 6), c7 = __shfl(cl, t + 7);
      float v0 = __shfl(vl, t),     v1 = __shfl(vl, t + 1);
      float v2 = __shfl(vl, t + 2), v3 = __shfl(vl, t + 3);
      float v4 = __shfl(vl, t + 4), v5 = __shfl(vl, t + 5);
      float v6 = __shfl(vl, t + 6), v7 = __shfl(vl, t + 7);
      float2 g0 = *(const float2*)(x + (size_t)c0 * EMB + d2);
      float2 g1 = *(const float2*)(x + (size_t)c1 * EMB + d2);
      float2 g2 = *(const float2*)(x + (size_t)c2 * EMB + d2);
      float2 g3 = *(const float2*)(x + (size_t)c3 * EMB + d2);
      float2 g4 = *(const float2*)(x + (size_t)c4 * EMB + d2);
      float2 g5 = *(const float2*)(x + (size_t)c5 * EMB + d2);
      float2 g6 = *(const float2*)(x + (size_t)c6 * EMB + d2);
      float2 g7 = *(const float2*)(x + (size_t)c7 * EMB + d2);
      ax += v0 * g0.x; ay += v0 * g0.y;
      ax += v1 * g1.x; ay += v1 * g1.y;
      ax += v2 * g2.x; ay += v2 * g2.y;
      ax += v3 * g3.x; ay += v3 * g3.y;
      ax += v4 * g4.x; ay += v4 * g4.y;
      ax += v5 * g5.x; ay += v5 * g5.y;
      ax += v6 * g6.x; ay += v6 * g6.y;
      ax += v7 * g7.x; ay += v7 * g7.y;
    }
    for (; t + 4 <= nb; t += 4) {
      int c0 = __shfl(cl, t),     c1 = __shfl(cl, t + 1);
      int c2 = __shfl(cl, t + 2), c3 = __shfl(cl, t + 3);
      float v0 = __shfl(vl, t),     v1 = __shfl(vl, t + 1);
      float v2 = __shfl(vl, t + 2), v3 = __shfl(vl, t + 3);
      float2 g0 = *(const float2*)(x + (size_t)c0 * EMB + d2);
      float2 g1 = *(const float2*)(x + (size_t)c1 * EMB + d2);
      float2 g2 = *(const float2*)(x + (size_t)c2 * EMB + d2);
      float2 g3 = *(const float2*)(x + (size_t)c3 * EMB + d2);
      ax += v0 * g0.x; ay += v0 * g0.y;
      ax += v1 * g1.x; ay += v1 * g1.y;
      ax += v2 * g2.x; ay += v2 * g2.y;
      ax += v3 * g3.x; ay += v3 * g3.y;
    }
    for (; t < nb; ++t) {
      int c = __shfl(cl, t);
      float v = __shfl(vl, t);
      float2 g = *(const float2*)(x + (size_t)c * EMB + d2);
      ax += v * g.x; ay += v * g.y;
    }
  }
  if (act) {
    float2 o; o.x = ax; o.y = ay;
    *(float2*)(out + (size_t)row * EMB + d2) = o;
  }
}

// ---------------- l2norm-combine (item conv epilogue) ----------------
__global__ void kcomb(const float* __restrict__ x0, const float* __restrict__ x1,
                      const float* __restrict__ x2, const float* __restrict__ bI,
                      float* __restrict__ emb) {
  int n = blockIdx.x * 4 + (threadIdx.x >> 6);
  int lane = threadIdx.x & 63;
  int d0 = lane, d1 = lane + 64;
  bool h1 = d1 < EMB;
  size_t base = (size_t)n * EMB;
  float v00 = x0[base + d0], v01 = h1 ? x0[base + d1] : 0.f;
  float v10 = x1[base + d0], v11 = h1 ? x1[base + d1] : 0.f;
  float v20 = x2[base + d0], v21 = h1 ? x2[base + d1] : 0.f;
  float q0 = v00 * v00 + v01 * v01;
  float q1 = v10 * v10 + v11 * v11;
  float q2 = v20 * v20 + v21 * v21;
  #pragma unroll
  for (int off = 32; off; off >>= 1) {
    q0 += __shfl_xor(q0, off);
    q1 += __shfl_xor(q1, off);
    q2 += __shfl_xor(q2, off);
  }
  float r0 = 1.f / fmaxf(sqrtf(q0), 1e-12f);
  float r1 = 1.f / fmaxf(sqrtf(q1), 1e-12f);
  float r2 = 1.f / fmaxf(sqrtf(q2), 1e-12f);
  float b0 = bI[0], b1 = bI[1], b2 = bI[2];
  emb[base + d0] = b0 * v00 * r0 + b1 * v10 * r1 + b2 * v20 * r2;
  if (h1) emb[base + d1] = b0 * v01 * r0 + b1 * v11 * r1 + b2 * v21 * r2;
}

// ---------------- GAT v4: lane = output row, h-row in registers ----------------
__global__ __launch_bounds__(256) void kgat(
    const float* __restrict__ emb, const int* __restrict__ items,
    const int* __restrict__ adj,
    const float* __restrict__ a0p, const float* __restrict__ a1p,
    const float* __restrict__ a2p, const float* __restrict__ a3p,
    float* __restrict__ hgat) {
  __shared__ __align__(16) float hl[64 * 108];     // 27.6 KB, rows 50..63 zeroed
  __shared__ __align__(16) float as[4 * 100];      // 1.6 KB
  __shared__ float alpha_lds[64 * 51];             // 13.1 KB
  __shared__ float wred[4][2][64];                 // 2 KB
  int b = blockIdx.x;
  int tid = threadIdx.x;
  for (int idx = tid; idx < 400; idx += 256) {
    int k = idx / 100, d = idx % 100;
    const float* ap = (k == 0) ? a0p : (k == 1) ? a1p : (k == 2) ? a2p : a3p;
    as[idx] = ap[d];
  }
  for (int idx = tid; idx < 64 * 50; idx += 256) {
    int i = idx / 50, d2 = (idx % 50) * 2;
    float2 v; v.x = 0.f; v.y = 0.f;
    if (i < NI) {
      int node = items[b * NI + i];
      if (node != 0) v = *(const float2*)(emb + (size_t)(node - 1) * EMB + d2);
    }
    *(float2*)&hl[i * 108 + d2] = v;
  }
  __syncthreads();
  int w = tid >> 6, lane = tid & 63;
  int j0 = w * 13;
  int nj = 50 - j0; if (nj > 13) nj = 13;          // 13,13,13,11

  // my h-row into registers (lanes >=50 read zeroed rows -> e = 0, harmless)
  float4 hreg[25];
  #pragma unroll
  for (int q = 0; q < 25; ++q) hreg[q] = *(const float4*)&hl[lane * 108 + q * 4];

  // adj row slice (clamp lane to stay in-bounds for lanes 50..63)
  int al_lane = (lane < NI) ? lane : NI - 1;
  const int* adjrow = adj + (size_t)b * (NI * NI) + al_lane * NI + j0;
  int adjv[13];
  #pragma unroll
  for (int t = 0; t < 13; ++t) adjv[t] = (t < nj) ? adjrow[t] : 0;

  // ---- scores: e[jj] for my row vs j0+jj ----
  float e[13];
  #pragma unroll
  for (int jj = 0; jj < 13; ++jj) {
    float acc = 0.f;
    if (jj < nj) {
      int j = j0 + jj;
      int k = adjv[jj] - 1; k = (k < 0) ? 0 : (k > 3) ? 3 : k;
      const float* aw = &as[k * 100];
      #pragma unroll
      for (int q = 0; q < 25; ++q) {
        float4 hj = *(const float4*)&hl[j * 108 + q * 4];   // uniform broadcast
        float4 a4 = *(const float4*)(aw + q * 4);           // <=4 distinct addrs
        float4 hm = hreg[q];
        acc += hm.x * hj.x * a4.x + hm.y * hj.y * a4.y
             + hm.z * hj.z * a4.z + hm.w * hj.w * a4.w;
      }
      acc = (acc >= 0.f) ? acc : 0.2f * acc;     // leakyrelu
      acc = (adjv[jj] == 0) ? -9e15f : acc;      // mask (matches reference)
    } else {
      acc = -INFINITY;                           // excluded from max/sum
    }
    e[jj] = acc;
  }

  // ---- softmax across waves (per-lane row-local) ----
  float mloc = -INFINITY;
  #pragma unroll
  for (int jj = 0; jj < 13; ++jj) if (jj < nj) mloc = fmaxf(mloc, e[jj]);
  wred[w][0][lane] = mloc;
  __syncthreads();
  float m = fmaxf(fmaxf(wred[0][0][lane], wred[1][0][lane]),
                  fmaxf(wred[2][0][lane], wred[3][0][lane]));
  float sloc = 0.f;
  #pragma unroll
  for (int jj = 0; jj < 13; ++jj) if (jj < nj) {
    e[jj] = expf(e[jj] - m);
    sloc += e[jj];
  }
  wred[w][1][lane] = sloc;
  __syncthreads();
  float s = (wred[0][1][lane] + wred[1][1][lane]) +
            (wred[2][1][lane] + wred[3][1][lane]);
  float inv = 1.f / s;
  #pragma unroll
  for (int jj = 0; jj < 13; ++jj) if (jj < nj)
    alpha_lds[lane * 51 + j0 + jj] = e[jj] * inv;
  __syncthreads();

  // ---- PV: out[i][d] = sum_j alpha[i][j] * h[j][d]; wave w owns quads w+4t ----
  int nq = (w == 0) ? 7 : 6;
  float4 outq[7];
  #pragma unroll
  for (int t = 0; t < 7; ++t) outq[t] = make_float4(0.f, 0.f, 0.f, 0.f);
  for (int j = 0; j < NI; ++j) {
    float aj = alpha_lds[lane * 51 + j];        // stride 51 -> conflict-free
    #pragma unroll
    for (int t = 0; t < 7; ++t) {
      if (t < nq) {
        int q = w + 4 * t;
        float4 hv = *(const float4*)&hl[j * 108 + q * 4];   // uniform broadcast
        outq[t].x += aj * hv.x; outq[t].y += aj * hv.y;
        outq[t].z += aj * hv.z; outq[t].w += aj * hv.w;
      }
    }
  }
  if (lane < NI) {
    #pragma unroll
    for (int t = 0; t < 7; ++t) {
      if (t < nq) {
        int q = w + 4 * t;
        *(float4*)&hgat[((size_t)b * NI + lane) * EMB + q * 4] = outq[t];
      }
    }
  }
}

// ---------------- get_seq mix ----------------
__global__ void kseq(const float* __restrict__ emb, const int* __restrict__ rev,
                     const int* __restrict__ alias, const float* __restrict__ hgat,
                     float* __restrict__ hseq) {
  int idx = blockIdx.x * 256 + threadIdx.x;  // 2,560,000 exact
  int b = idx / 5000, r = idx % 5000, l = r / 100, d = r % 100;
  int node = rev[b * LL + l];
  float sh = (node == 0) ? 0.f : emb[(size_t)(node - 1) * EMB + d];
  int a = alias[b * LL + l];
  float shh = hgat[((size_t)b * NI + a) * EMB + d];
  hseq[idx] = 0.2f * sh + 0.8f * shh;
}

// ---------------- weight prep: transposes + pos@W1a ----------------
__global__ void kprep_t(const float* __restrict__ w1W, const float* __restrict__ g1W,
                        const float* __restrict__ g2W, float* __restrict__ w1t2,
                        float* __restrict__ g1t, float* __restrict__ g2t) {
  int idx = blockIdx.x * 256 + threadIdx.x;
  if (idx >= 10000) return;
  int c = idx / 100, o = idx % 100;
  w1t2[c * 100 + o] = w1W[o * 200 + 100 + c];
  g1t[c * 100 + o] = g1W[o * 100 + c];
  g2t[c * 100 + o] = g2W[o * 100 + c];
}

__global__ void kprep_pos(const float* __restrict__ posE, const float* __restrict__ w1W,
                          const float* __restrict__ w1b, float* __restrict__ posW) {
  int idx = blockIdx.x * 256 + threadIdx.x;
  if (idx >= 5000) return;
  int l = idx / 100, o = idx % 100;
  float acc = w1b[o];
  for (int c = 0; c < 100; ++c) acc += posE[l * 100 + c] * w1W[o * 200 + c];
  posW[idx] = acc;
}

// ---------------- soft attention (block per batch, register-tiled) ----------------
__global__ __launch_bounds__(256) void ksoft(
    const float* __restrict__ hseqG, const float* __restrict__ slenp,
    const int* __restrict__ maskp,
    const float* __restrict__ posW, const float* __restrict__ w1t2,
    const float* __restrict__ glu1t, const float* __restrict__ glu1b,
    const float* __restrict__ glu2t, const float* __restrict__ w2,
    float* __restrict__ sel) {
  __shared__ float hq[LL * 101];       // 20.2 KB
  __shared__ float nh[LL * 100];       // 20 KB
  __shared__ float red[25 * 52];       // 5.2 KB  (red[og][l])
  __shared__ float hs_s[100];
  __shared__ float g_s[100];
  __shared__ float beta_s[LL];
  int b = blockIdx.x, tid = threadIdx.x;
  for (int idx = tid; idx < LL * 100; idx += 256) {
    int l = idx / 100, d = idx % 100;
    hq[l * 101 + d] = hseqG[((size_t)b * LL + l) * 100 + d];
  }
  __syncthreads();
  if (tid < 100) {
    float s = 0.f;
    for (int l = 0; l < LL; ++l) s += hq[l * 101 + tid];
    hs_s[tid] = s / slenp[b];
  }
  __syncthreads();
  if (tid < 100) {
    float acc = 0.f;
    for (int c = 0; c < 100; ++c) acc += hs_s[c] * glu2t[c * 100 + tid];
    g_s[tid] = acc;
  }
  // ---- phase B: nh = tanh(hq @ w1t2 + posW) ----
  int lg = tid / 25, og = tid % 25;    // valid when tid < 250
  if (tid < 250) {
    float acc[5][4];
    #pragma unroll
    for (int j = 0; j < 5; ++j) {
      float4 p = *(const float4*)&posW[(lg * 5 + j) * 100 + og * 4];
      acc[j][0] = p.x; acc[j][1] = p.y; acc[j][2] = p.z; acc[j][3] = p.w;
    }
    for (int c = 0; c < 100; ++c) {
      float4 wv = *(const float4*)&w1t2[c * 100 + og * 4];
      float hv[5];
      #pragma unroll
      for (int j = 0; j < 5; ++j) hv[j] = hq[(lg * 5 + j) * 101 + c];
      #pragma unroll
      for (int j = 0; j < 5; ++j) {
        acc[j][0] += hv[j] * wv.x;
        acc[j][1] += hv[j] * wv.y;
        acc[j][2] += hv[j] * wv.z;
        acc[j][3] += hv[j] * wv.w;
      }
    }
    #pragma unroll
    for (int j = 0; j < 5; ++j) {
      float4 t;
      t.x = tanhf(acc[j][0]); t.y = tanhf(acc[j][1]);
      t.z = tanhf(acc[j][2]); t.w = tanhf(acc[j][3]);
      *(float4*)&nh[(lg * 5 + j) * 100 + og * 4] = t;
    }
  }
  __syncthreads();  // nh + g_s visible
  // ---- phase C: val = sigmoid(nh @ glu1t + g + b) * w2; row-sum -> red ----
  if (tid < 250) {
    float4 gb = *(const float4*)&glu1b[og * 4];
    float4 gg = *(const float4*)&g_s[og * 4];
    float base0 = gg.x + gb.x, base1 = gg.y + gb.y, base2 = gg.z + gb.z, base3 = gg.w + gb.w;
    float acc[5][4];
    #pragma unroll
    for (int j = 0; j < 5; ++j) {
      acc[j][0] = base0; acc[j][1] = base1; acc[j][2] = base2; acc[j][3] = base3;
    }
    for (int c = 0; c < 100; ++c) {
      float4 wv = *(const float4*)&glu1t[c * 100 + og * 4];
      float hv[5];
      #pragma unroll
      for (int j = 0; j < 5; ++j) hv[j] = nh[(lg * 5 + j) * 100 + c];
      #pragma unroll
      for (int j = 0; j < 5; ++j) {
        acc[j][0] += hv[j] * wv.x;
        acc[j][1] += hv[j] * wv.y;
        acc[j][2] += hv[j] * wv.z;
        acc[j][3] += hv[j] * wv.w;
      }
    }
    float4 w2v = *(const float4*)&w2[og * 4];
    #pragma unroll
    for (int j = 0; j < 5; ++j) {
      float s0 = w2v.x / (1.f + expf(-acc[j][0]));
      float s1 = w2v.y / (1.f + expf(-acc[j][1]));
      float s2 = w2v.z / (1.f + expf(-acc[j][2]));
      float s3 = w2v.w / (1.f + expf(-acc[j][3]));
      red[og * 52 + lg * 5 + j] = (s0 + s1) + (s2 + s3);
    }
  }
  __syncthreads();
  if (tid < LL) {
    float s = 0.f;
    for (int og2 = 0; og2 < 25; ++og2) s += red[og2 * 52 + tid];
    beta_s[tid] = s * (float)maskp[b * LL + tid];
  }
  __syncthreads();
  if (tid < 100) {
    float acc = 0.f;
    for (int l = 0; l < LL; ++l) acc += beta_s[l] * hq[l * 101 + tid];
    sel[(size_t)b * 100 + tid] = acc;
  }
}

// ---------------- session conv: dense [512,512] @ [512,100] ----------------
__global__ void ksess(const float* __restrict__ adjS, const float* __restrict__ x,
                      float* __restrict__ out) {
  int b = blockIdx.x, d = threadIdx.x;
  if (d >= 100) return;
  const float* ar = adjS + (size_t)b * BB;
  float a0 = 0.f, a1 = 0.f, a2 = 0.f, a3 = 0.f;
  for (int j = 0; j < BB; j += 4) {
    a0 += ar[j]     * x[(j)     * 100 + d];
    a1 += ar[j + 1] * x[(j + 1) * 100 + d];
    a2 += ar[j + 2] * x[(j + 2) * 100 + d];
    a3 += ar[j + 3] * x[(j + 3) * 100 + d];
  }
  out[(size_t)b * 100 + d] = (a0 + a1) + (a2 + a3);
}

__global__ void ksesscomb(const float* __restrict__ x0, const float* __restrict__ x1,
                          const float* __restrict__ x2, const float* __restrict__ aS,
                          float* __restrict__ out) {
  int b = blockIdx.x * 4 + (threadIdx.x >> 6);
  int lane = threadIdx.x & 63;
  int d0 = lane, d1 = lane + 64;
  bool h1 = d1 < EMB;
  size_t base = (size_t)b * EMB;
  float v00 = x0[base + d0], v01 = h1 ? x0[base + d1] : 0.f;
  float v10 = x1[base + d0], v11 = h1 ? x1[base + d1] : 0.f;
  float v20 = x2[base + d0], v21 = h1 ? x2[base + d1] : 0.f;
  float q0 = v00 * v00 + v01 * v01;
  float q1 = v10 * v10 + v11 * v11;
  float q2 = v20 * v20 + v21 * v21;
  #pragma unroll
  for (int off = 32; off; off >>= 1) {
    q0 += __shfl_xor(q0, off);
    q1 += __shfl_xor(q1, off);
    q2 += __shfl_xor(q2, off);
  }
  float r0 = 1.f / fmaxf(sqrtf(q0), 1e-12f);
  float r1 = 1.f / fmaxf(sqrtf(q1), 1e-12f);
  float r2 = 1.f / fmaxf(sqrtf(q2), 1e-12f);
  float b0 = aS[0], b1 = aS[1], b2 = aS[2];
  // seq_h = sel1+sel2 = 2 * session_conv output
  out[base + d0] = 2.f * (b0 * v00 * r0 + b1 * v10 * r1 + b2 * v20 * r2);
  if (h1) out[base + d1] = 2.f * (b0 * v01 * r0 + b1 * v11 * r1 + b2 * v21 * r2);
}

// ---------------- bf16 hi/lo split prep ----------------
// B = 2*emb_gnn -> [40000][128] padded; A = seqh -> [512][128] padded
__global__ void kprepB(const float* __restrict__ emb, unsigned short* __restrict__ bHi,
                       unsigned short* __restrict__ bLo) {
  int idx = blockIdx.x * 256 + threadIdx.x;  // 5,120,000 exact
  int n = idx >> 7, k = idx & 127;
  float v = (k < EMB) ? 2.f * emb[(size_t)n * EMB + k] : 0.f;
  __hip_bfloat16 h = __float2bfloat16(v);
  float rem = v - __bfloat162float(h);
  __hip_bfloat16 l = __float2bfloat16(rem);
  bHi[idx] = *reinterpret_cast<unsigned short*>(&h);
  bLo[idx] = *reinterpret_cast<unsigned short*>(&l);
}

__global__ void kprepA(const float* __restrict__ seqh, unsigned short* __restrict__ aHi,
                       unsigned short* __restrict__ aLo) {
  int idx = blockIdx.x * 256 + threadIdx.x;  // 65,536 exact
  int n = idx >> 7, k = idx & 127;
  float v = (k < EMB) ? seqh[(size_t)n * EMB + k] : 0.f;
  __hip_bfloat16 h = __float2bfloat16(v);
  float rem = v - __bfloat162float(h);
  __hip_bfloat16 l = __float2bfloat16(rem);
  aHi[idx] = *reinterpret_cast<unsigned short*>(&h);
  aLo[idx] = *reinterpret_cast<unsigned short*>(&l);
}

// ---------------- scores GEMM v3: 64x64 tile, 2 b-steps per block ----------------
__global__ __launch_bounds__(256) void kscoresM(
    const unsigned short* __restrict__ aHi, const unsigned short* __restrict__ aLo,
    const unsigned short* __restrict__ bHi, const unsigned short* __restrict__ bLo,
    float* __restrict__ outS) {
  __shared__ __align__(16) unsigned short Bh[64 * 136];  // 136 = 128 + 8 pad
  __shared__ __align__(16) unsigned short Bl[64 * 136];
  int tid = threadIdx.x;
  int n0 = blockIdx.y * 64;
  int bbase = blockIdx.x * 128;          // 2 b-steps of 64 rows
  int w = tid >> 6, lane = tid & 63;
  int ln = lane & 15, quad = lane >> 4;

  // A fragments for BOTH b-steps, loaded up-front (L2-hot, 256 KB total set)
  const unsigned short* aRowH0 = aHi + (size_t)(bbase + w * 16 + ln) * 128 + quad * 8;
  const unsigned short* aRowL0 = aLo + (size_t)(bbase + w * 16 + ln) * 128 + quad * 8;
  const unsigned short* aRowH1 = aRowH0 + 64 * 128;
  const unsigned short* aRowL1 = aRowL0 + 64 * 128;
  s16x8 ah0[4], al0[4], ah1[4], al1[4];
  #pragma unroll
  for (int s = 0; s < 4; ++s) {
    ah0[s] = *(const s16x8*)(aRowH0 + s * 32);
    al0[s] = *(const s16x8*)(aRowL0 + s * 32);
    ah1[s] = *(const s16x8*)(aRowH1 + s * 32);
    al1[s] = *(const s16x8*)(aRowL1 + s * 32);
  }

  // stage B tile (64 rows x 128 k, hi+lo) into LDS -- once for both b-steps
  #pragma unroll
  for (int it = 0; it < 4; ++it) {
    int seg = tid + it * 256;      // 0..1023
    int r = seg >> 4, q = seg & 15;
    *(s16x8*)&Bh[r * 136 + q * 8] = *(const s16x8*)&bHi[(size_t)(n0 + r) * 128 + q * 8];
    *(s16x8*)&Bl[r * 136 + q * 8] = *(const s16x8*)&bLo[(size_t)(n0 + r) * 128 + q * 8];
  }
  __syncthreads();

  // ---- b-step 0 ----
  f32x4 acc[4];
  #pragma unroll
  for (int t = 0; t < 4; ++t) acc[t] = (f32x4){0.f, 0.f, 0.f, 0.f};
  #pragma unroll
  for (int s = 0; s < 4; ++s) {
    #pragma unroll
    for (int t = 0; t < 4; ++t) {
      s16x8 bh = *(const s16x8*)&Bh[(t * 16 + ln) * 136 + s * 32 + quad * 8];
      s16x8 bl = *(const s16x8*)&Bl[(t * 16 + ln) * 136 + s * 32 + quad * 8];
      acc[t] = __builtin_amdgcn_mfma_f32_16x16x32_bf16(ah0[s], bh, acc[t], 0, 0, 0);
      acc[t] = __builtin_amdgcn_mfma_f32_16x16x32_bf16(al0[s], bh, acc[t], 0, 0, 0);
      acc[t] = __builtin_amdgcn_mfma_f32_16x16x32_bf16(ah0[s], bl, acc[t], 0, 0, 0);
    }
  }
  {
    int brow = bbase + w * 16 + quad * 4;
    #pragma unroll
    for (int t = 0; t < 4; ++t) {
      int ncol = n0 + t * 16 + ln;
      #pragma unroll
      for (int r = 0; r < 4; ++r) {
        outS[(size_t)(brow + r) * N_NODE + ncol] = acc[t][r];
      }
    }
  }

  // ---- b-step 1 ----
  #pragma unroll
  for (int t = 0; t < 4; ++t) acc[t] = (f32x4){0.f, 0.f, 0.f, 0.f};
  #pragma unroll
  for (int s = 0; s < 4; ++s) {
    #pragma unroll
    for (int t = 0; t < 4; ++t) {
      s16x8 bh = *(const s16x8*)&Bh[(t * 16 + ln) * 136 + s * 32 + quad * 8];
      s16x8 bl = *(const s16x8*)&Bl[(t * 16 + ln) * 136 + s * 32 + quad * 8];
      acc[t] = __builtin_amdgcn_mfma_f32_16x16x32_bf16(ah1[s], bh, acc[t], 0, 0, 0);
      acc[t] = __builtin_amdgcn_mfma_f32_16x16x32_bf16(al1[s], bh, acc[t], 0, 0, 0);
      acc[t] = __builtin_amdgcn_mfma_f32_16x16x32_bf16(ah1[s], bl, acc[t], 0, 0, 0);
    }
  }
  {
    int brow = bbase + 64 + w * 16 + quad * 4;
    #pragma unroll
    for (int t = 0; t < 4; ++t) {
      int ncol = n0 + t * 16 + ln;
      #pragma unroll
      for (int r = 0; r < 4; ++r) {
        outS[(size_t)(brow + r) * N_NODE + ncol] = acc[t][r];
      }
    }
  }
}

// ---------------- per-row logsumexp + target score ----------------
__global__ __launch_bounds__(256) void klse(const float* __restrict__ outS,
                                            const int* __restrict__ tar,
                                            float* __restrict__ part) {
  __shared__ float ms[256], ss[256];
  int b = blockIdx.x, tid = threadIdx.x;
  const float2* sp = (const float2*)(outS + (size_t)b * N_NODE);
  float m = -INFINITY, s = 0.f;
  for (int i = tid; i < N_NODE / 2; i += 256) {
    float2 v = sp[i];
    float mx = fmaxf(v.x, v.y);
    float add = expf(v.x - mx) + expf(v.y - mx);
    if (mx > m) { s = s * expf(m - mx) + add; m = mx; }
    else s += add * expf(mx - m);
  }
  ms[tid] = m; ss[tid] = s;
  __syncthreads();
  for (int st = 128; st; st >>= 1) {
    if (tid < st) {
      float m2 = ms[tid + st], s2 = ss[tid + st];
      float M = fmaxf(ms[tid], m2);
      ss[tid] = ss[tid] * expf(ms[tid] - M) + s2 * expf(m2 - M);
      ms[tid] = M;
    }
    __syncthreads();
  }
  if (tid == 0) {
    float tsc = outS[(size_t)b * N_NODE + tar[b]];
    part[b] = tsc - (ms[0] + logf(ss[0]));
  }
}

__global__ void kfinal(const float* __restrict__ part, float* __restrict__ out) {
  __shared__ float red[256];
  int tid = threadIdx.x;
  red[tid] = part[tid] + part[tid + 256];
  __syncthreads();
  for (int st = 128; st; st >>= 1) {
    if (tid < st) red[tid] += red[tid + st];
    __syncthreads();
  }
  if (tid == 0) {
    out[0] = 0.f;                        // con_loss
    out[1] = -red[0] / (float)BB;        // loss
  }
}

extern "C" void kernel_launch(void* const* d_in, const int* in_sizes, int n_in,
                              void* d_out, int out_size, void* d_ws, size_t ws_size,
                              hipStream_t stream) {
  const int* tar    = (const int*)d_in[0];
  const int* rev    = (const int*)d_in[1];
  const int* maskp  = (const int*)d_in[2];
  const float* slen = (const float*)d_in[3];
  const float* sadj = (const float*)d_in[4];
  const int* items  = (const int*)d_in[6];
  const int* adjp   = (const int*)d_in[7];
  const int* alias  = (const int*)d_in[8];
  const int* grows  = (const int*)d_in[9];
  const int* gcols  = (const int*)d_in[10];
  const float* gvals = (const float*)d_in[11];
  const float* nemb = (const float*)d_in[12];
  const float* bI   = (const float*)d_in[13];
  const float* aS   = (const float*)d_in[14];
  const float* a0p  = (const float*)d_in[15];
  const float* a1p  = (const float*)d_in[16];
  const float* a2p  = (const float*)d_in[17];
  const float* a3p  = (const float*)d_in[18];
  const float* w1W  = (const float*)d_in[19];
  const float* w1b  = (const float*)d_in[20];
  const float* w2p  = (const float*)d_in[21];
  const float* g1W  = (const float*)d_in[22];
  const float* g1b  = (const float*)d_in[23];
  const float* g2W  = (const float*)d_in[24];
  const float* posE = (const float*)d_in[25];

  float* W = (float*)d_ws;
  size_t o = 0;
  float* emb_gnn = W + o; o += (size_t)N_NODE * EMB;   // 4,000,000
  float* x1      = W + o; o += (size_t)N_NODE * EMB;   // reused: hgat, then bHi
  float* x2      = W + o; o += (size_t)N_NODE * EMB;   // reused: hseq, then bLo
  float* sel     = W + o; o += (size_t)BB * EMB;
  float* y1      = W + o; o += (size_t)BB * EMB;
  float* y2      = W + o; o += (size_t)BB * EMB;
  float* seqh    = W + o; o += (size_t)BB * EMB;
  float* posW    = W + o; o += 5120;
  float* w1t2    = W + o; o += 10000;
  float* glu1t   = W + o; o += 10000;
  float* glu2t   = W + o; o += 10000;
  int2* colval   = (int2*)(W + o); o += (size_t)2 * EDG;  // merged {col,val}
  float* part    = W + o; o += 512;
  int* counts = (int*)(W + o); o += N_NODE;
  int* starts = (int*)(W + o); o += N_NODE;
  int* cursor = (int*)(W + o); o += N_NODE;
  int* scantmp = (int*)(W + o); o += N_NODE;
  int* blocksums = (int*)(W + o); o += 256;
  unsigned short* aHi = (unsigned short*)(W + o); o += 32768;  // 512*128 bf16 = 32768 floats/2
  unsigned short* aLo = (unsigned short*)(W + o); o += 32768;
  // hgat/hseq alias x1/x2 (dead after kcomb); bHi/bLo alias x1/x2 (hgat dead after
  // kseq, hseq dead after ksoft; each needs 2.56M floats of the 4M region)
  float* hgat = x1;
  float* hseq = x2;
  unsigned short* bHi = (unsigned short*)x1;   // 5.12M u16 = 2.56M floats <= 4M
  unsigned short* bLo = (unsigned short*)x2;

  float* outF = (float*)d_out;
  float* outScores = outF + 2;

  hipMemsetAsync(counts, 0, N_NODE * sizeof(int), stream);
  khist<<<EDG / 256, 256, 0, stream>>>(grows, counts);
  kscan1<<<SCAN_BLOCKS, 256, 0, stream>>>(counts, scantmp, blocksums, N_NODE);
  kscan2<<<1, 256, 0, stream>>>(blocksums, SCAN_BLOCKS);
  kscan3<<<SCAN_BLOCKS, 256, 0, stream>>>(scantmp, blocksums, starts, cursor, N_NODE);
  kfill<<<((EDG + 1023) / 1024) * 8, 256, 0, stream>>>(grows, gcols, gvals, cursor, colval);
  kspmm<<<N_NODE / 4, 256, 0, stream>>>(starts, counts, colval, nemb, x1);
  kspmm<<<N_NODE / 4, 256, 0, stream>>>(starts, counts, colval, x1, x2);
  kcomb<<<N_NODE / 4, 256, 0, stream>>>(nemb, x1, x2, bI, emb_gnn);
  kgat<<<BB, 256, 0, stream>>>(emb_gnn, items, adjp, a0p, a1p, a2p, a3p, hgat);
  kseq<<<(BB * LL * EMB) / 256, 256, 0, stream>>>(emb_gnn, rev, alias, hgat, hseq);
  kprep_t<<<40, 256, 0, stream>>>(w1W, g1W, g2W, w1t2, glu1t, glu2t);
  kprep_pos<<<20, 256, 0, stream>>>(posE, w1W, w1b, posW);
  ksoft<<<BB, 256, 0, stream>>>(hseq, slen, maskp, posW, w1t2, glu1t, g1b, glu2t, w2p, sel);
  // hgat(x1) dead after kseq, hseq(x2) dead after ksoft -> safe to build bHi/bLo now
  kprepB<<<(N_NODE * 128) / 256, 256, 0, stream>>>(emb_gnn, bHi, bLo);
  ksess<<<BB, 128, 0, stream>>>(sadj, sel, y1);
  ksess<<<BB, 128, 0, stream>>>(sadj, y1, y2);
  ksesscomb<<<BB / 4, 256, 0, stream>>>(sel, y1, y2, aS, seqh);
  kprepA<<<(BB * 128) / 256, 256, 0, stream>>>(seqh, aHi, aLo);
  kscoresM<<<dim3(4, N_NODE / 64), 256, 0, stream>>>(aHi, aLo, bHi, bLo, outScores);
  klse<<<BB, 256, 0, stream>>>(outScores, tar, part);
  kfinal<<<1, 256, 0, stream>>>(part, outF);
}

// Round 8
// 504.806 us; speedup vs baseline: 1.1104x; 1.0707x over previous
//
#include <hip/hip_runtime.h>
#include <hip/hip_bf16.h>
#include <math.h>

#define N_NODE 40000
#define EMB 100
#define BB 512
#define LL 50
#define NI 50
#define EDG 800000
#define SCAN_BLOCKS 157  // ceil(40000/256)
#define NBLK 625         // N_NODE/64 score column blocks

typedef short s16x8 __attribute__((ext_vector_type(8)));   // 8 bf16 = 4 VGPRs
typedef float f32x4 __attribute__((ext_vector_type(4)));   // MFMA 16x16 accumulator

// ---------------- CSR build ----------------
__global__ void khist(const int* __restrict__ rows, int* __restrict__ counts) {
  int e = blockIdx.x * 256 + threadIdx.x;
  atomicAdd(&counts[rows[e]], 1);
}

// block-local exclusive scan (256 elems/block) + block sums
__global__ __launch_bounds__(256) void kscan1(const int* __restrict__ counts,
                                              int* __restrict__ scanout,
                                              int* __restrict__ blocksums, int n) {
  __shared__ int wsum[4];
  int tid = threadIdx.x;
  int i = blockIdx.x * 256 + tid;
  int v = (i < n) ? counts[i] : 0;
  int x = v;
  #pragma unroll
  for (int off = 1; off < 64; off <<= 1) {
    int t = __shfl_up(x, off, 64);
    if ((tid & 63) >= off) x += t;
  }
  int w = tid >> 6, lane = tid & 63;
  if (lane == 63) wsum[w] = x;
  __syncthreads();
  int woff = 0;
  #pragma unroll
  for (int k = 0; k < 4; ++k) woff += (k < w) ? wsum[k] : 0;
  int incl = x + woff;
  if (i < n) scanout[i] = incl - v;  // block-local exclusive
  if (tid == 255) blocksums[blockIdx.x] = incl;
}

// scan the block sums (one block, 256 threads >= 157)
__global__ __launch_bounds__(256) void kscan2(int* __restrict__ blocksums, int nb) {
  __shared__ int wsum[4];
  int tid = threadIdx.x;
  int v = (tid < nb) ? blocksums[tid] : 0;
  int x = v;
  #pragma unroll
  for (int off = 1; off < 64; off <<= 1) {
    int t = __shfl_up(x, off, 64);
    if ((tid & 63) >= off) x += t;
  }
  int w = tid >> 6, lane = tid & 63;
  if (lane == 63) wsum[w] = x;
  __syncthreads();
  int woff = 0;
  #pragma unroll
  for (int k = 0; k < 4; ++k) woff += (k < w) ? wsum[k] : 0;
  if (tid < nb) blocksums[tid] = x + woff - v;  // exclusive
}

// add block offsets, produce starts + cursor
__global__ __launch_bounds__(256) void kscan3(const int* __restrict__ scanout,
                                              const int* __restrict__ blocksums,
                                              int* __restrict__ starts,
                                              int* __restrict__ cursor, int n) {
  int i = blockIdx.x * 256 + threadIdx.x;
  if (i < n) {
    int s = scanout[i] + blocksums[blockIdx.x];
    starts[i] = s;
    cursor[i] = s;
  }
}

// fill v3: XCD-partitioned scatter (see r6 notes: kills cross-XCD dirty-line
// duplication; WRITE 51 MB -> ~10 MB).
__global__ __launch_bounds__(256) void kfill(const int* __restrict__ rows,
                                             const int* __restrict__ cols,
                                             const float* __restrict__ vals,
                                             int* __restrict__ cursor,
                                             int2* __restrict__ colval) {
  int q = blockIdx.x & 7;                 // partition == XCD (bid%8 round-robin)
  int chunk = blockIdx.x >> 3;
  int e0 = (chunk * 256 + threadIdx.x) * 4;
  int rlo = q * 5000, rhi = rlo + 5000;
  if (e0 + 3 < EDG) {
    int4 r4 = *(const int4*)(rows + e0);
    int rr0 = r4.x, rr1 = r4.y, rr2 = r4.z, rr3 = r4.w;
    if (rr0 >= rlo && rr0 < rhi) {
      int p = atomicAdd(&cursor[rr0], 1);
      int2 cv; cv.x = cols[e0];     cv.y = __float_as_int(vals[e0]);
      colval[p] = cv;
    }
    if (rr1 >= rlo && rr1 < rhi) {
      int p = atomicAdd(&cursor[rr1], 1);
      int2 cv; cv.x = cols[e0 + 1]; cv.y = __float_as_int(vals[e0 + 1]);
      colval[p] = cv;
    }
    if (rr2 >= rlo && rr2 < rhi) {
      int p = atomicAdd(&cursor[rr2], 1);
      int2 cv; cv.x = cols[e0 + 2]; cv.y = __float_as_int(vals[e0 + 2]);
      colval[p] = cv;
    }
    if (rr3 >= rlo && rr3 < rhi) {
      int p = atomicAdd(&cursor[rr3], 1);
      int2 cv; cv.x = cols[e0 + 3]; cv.y = __float_as_int(vals[e0 + 3]);
      colval[p] = cv;
    }
  } else {
    for (int k = 0; k < 4; ++k) {
      int e = e0 + k;
      if (e < EDG) {
        int r = rows[e];
        if (r >= rlo && r < rhi) {
          int p = atomicAdd(&cursor[r], 1);
          int2 cv; cv.x = cols[e]; cv.y = __float_as_int(vals[e]);
          colval[p] = cv;
        }
      }
    }
  }
}

// ---------------- gather SpMM (wave per row, batched edges + 8x MLP) ----------
__global__ __launch_bounds__(256) void kspmm(const int* __restrict__ starts,
                                             const int* __restrict__ counts,
                                             const int2* __restrict__ colval,
                                             const float* __restrict__ x,
                                             float* __restrict__ out) {
  int row = blockIdx.x * 4 + (threadIdx.x >> 6);
  int lane = threadIdx.x & 63;
  int s = starts[row], cnt = counts[row];
  bool act = lane < 50;
  int d2 = (act ? lane : 49) * 2;      // clamped: inactive lanes re-read last pair
  float ax = 0.f, ay = 0.f;
  for (int base = 0; base < cnt; base += 64) {
    int nb = cnt - base; if (nb > 64) nb = 64;
    int cl = 0; float vl = 0.f;
    if (lane < nb) {
      int2 cv = colval[s + base + lane];
      cl = cv.x; vl = __int_as_float(cv.y);
    }
    int t = 0;
    for (; t + 8 <= nb; t += 8) {
      int c0 = __shfl(cl, t),     c1 = __shfl(cl, t + 1);
      int c2 = __shfl(cl, t + 2), c3 = __shfl(cl, t + 3);
      int c4 = __shfl(cl, t + 4), c5 = __shfl(cl, t + 5);
      int c6 = __shfl(cl, t + 6), c7 = __shfl(cl, t + 7);
      float v0 = __shfl(vl, t),     v1 = __shfl(vl, t + 1);
      float v2 = __shfl(vl, t + 2), v3 = __shfl(vl, t + 3);
      float v4 = __shfl(vl, t + 4), v5 = __shfl(vl, t + 5);
      float v6 = __shfl(vl, t + 6), v7 = __shfl(vl, t + 7);
      float2 g0 = *(const float2*)(x + (size_t)c0 * EMB + d2);
      float2 g1 = *(const float2*)(x + (size_t)c1 * EMB + d2);
      float2 g2 = *(const float2*)(x + (size_t)c2 * EMB + d2);
      float2 g3 = *(const float2*)(x + (size_t)c3 * EMB + d2);
      float2 g4 = *(const float2*)(x + (size_t)c4 * EMB + d2);
      float2 g5 = *(const float2*)(x + (size_t)c5 * EMB + d2);
      float2 g6 = *(const float2*)(x + (size_t)c6 * EMB + d2);
      float2 g7 = *(const float2*)(x + (size_t)c7 * EMB + d2);
      ax += v0 * g0.x; ay += v0 * g0.y;
      ax += v1 * g1.x; ay += v1 * g1.y;
      ax += v2 * g2.x; ay += v2 * g2.y;
      ax += v3 * g3.x; ay += v3 * g3.y;
      ax += v4 * g4.x; ay += v4 * g4.y;
      ax += v5 * g5.x; ay += v5 * g5.y;
      ax += v6 * g6.x; ay += v6 * g6.y;
      ax += v7 * g7.x; ay += v7 * g7.y;
    }
    for (; t + 4 <= nb; t += 4) {
      int c0 = __shfl(cl, t),     c1 = __shfl(cl, t + 1);
      int c2 = __shfl(cl, t + 2), c3 = __shfl(cl, t + 3);
      float v0 = __shfl(vl, t),     v1 = __shfl(vl, t + 1);
      float v2 = __shfl(vl, t + 2), v3 = __shfl(vl, t + 3);
      float2 g0 = *(const float2*)(x + (size_t)c0 * EMB + d2);
      float2 g1 = *(const float2*)(x + (size_t)c1 * EMB + d2);
      float2 g2 = *(const float2*)(x + (size_t)c2 * EMB + d2);
      float2 g3 = *(const float2*)(x + (size_t)c3 * EMB + d2);
      ax += v0 * g0.x; ay += v0 * g0.y;
      ax += v1 * g1.x; ay += v1 * g1.y;
      ax += v2 * g2.x; ay += v2 * g2.y;
      ax += v3 * g3.x; ay += v3 * g3.y;
    }
    for (; t < nb; ++t) {
      int c = __shfl(cl, t);
      float v = __shfl(vl, t);
      float2 g = *(const float2*)(x + (size_t)c * EMB + d2);
      ax += v * g.x; ay += v * g.y;
    }
  }
  if (act) {
    float2 o; o.x = ax; o.y = ay;
    *(float2*)(out + (size_t)row * EMB + d2) = o;
  }
}

// ---------------- l2norm-combine (item conv epilogue) ----------------
__global__ void kcomb(const float* __restrict__ x0, const float* __restrict__ x1,
                      const float* __restrict__ x2, const float* __restrict__ bI,
                      float* __restrict__ emb) {
  int n = blockIdx.x * 4 + (threadIdx.x >> 6);
  int lane = threadIdx.x & 63;
  int d0 = lane, d1 = lane + 64;
  bool h1 = d1 < EMB;
  size_t base = (size_t)n * EMB;
  float v00 = x0[base + d0], v01 = h1 ? x0[base + d1] : 0.f;
  float v10 = x1[base + d0], v11 = h1 ? x1[base + d1] : 0.f;
  float v20 = x2[base + d0], v21 = h1 ? x2[base + d1] : 0.f;
  float q0 = v00 * v00 + v01 * v01;
  float q1 = v10 * v10 + v11 * v11;
  float q2 = v20 * v20 + v21 * v21;
  #pragma unroll
  for (int off = 32; off; off >>= 1) {
    q0 += __shfl_xor(q0, off);
    q1 += __shfl_xor(q1, off);
    q2 += __shfl_xor(q2, off);
  }
  float r0 = 1.f / fmaxf(sqrtf(q0), 1e-12f);
  float r1 = 1.f / fmaxf(sqrtf(q1), 1e-12f);
  float r2 = 1.f / fmaxf(sqrtf(q2), 1e-12f);
  float b0 = bI[0], b1 = bI[1], b2 = bI[2];
  emb[base + d0] = b0 * v00 * r0 + b1 * v10 * r1 + b2 * v20 * r2;
  if (h1) emb[base + d1] = b0 * v01 * r0 + b1 * v11 * r1 + b2 * v21 * r2;
}

// ---------------- GAT v4: lane = output row, h-row in registers ----------------
__global__ __launch_bounds__(256) void kgat(
    const float* __restrict__ emb, const int* __restrict__ items,
    const int* __restrict__ adj,
    const float* __restrict__ a0p, const float* __restrict__ a1p,
    const float* __restrict__ a2p, const float* __restrict__ a3p,
    float* __restrict__ hgat) {
  __shared__ __align__(16) float hl[64 * 108];     // 27.6 KB, rows 50..63 zeroed
  __shared__ __align__(16) float as[4 * 100];      // 1.6 KB
  __shared__ float alpha_lds[64 * 51];             // 13.1 KB
  __shared__ float wred[4][2][64];                 // 2 KB
  int b = blockIdx.x;
  int tid = threadIdx.x;
  for (int idx = tid; idx < 400; idx += 256) {
    int k = idx / 100, d = idx % 100;
    const float* ap = (k == 0) ? a0p : (k == 1) ? a1p : (k == 2) ? a2p : a3p;
    as[idx] = ap[d];
  }
  for (int idx = tid; idx < 64 * 50; idx += 256) {
    int i = idx / 50, d2 = (idx % 50) * 2;
    float2 v; v.x = 0.f; v.y = 0.f;
    if (i < NI) {
      int node = items[b * NI + i];
      if (node != 0) v = *(const float2*)(emb + (size_t)(node - 1) * EMB + d2);
    }
    *(float2*)&hl[i * 108 + d2] = v;
  }
  __syncthreads();
  int w = tid >> 6, lane = tid & 63;
  int j0 = w * 13;
  int nj = 50 - j0; if (nj > 13) nj = 13;          // 13,13,13,11

  // my h-row into registers (lanes >=50 read zeroed rows -> e = 0, harmless)
  float4 hreg[25];
  #pragma unroll
  for (int q = 0; q < 25; ++q) hreg[q] = *(const float4*)&hl[lane * 108 + q * 4];

  // adj row slice (clamp lane to stay in-bounds for lanes 50..63)
  int al_lane = (lane < NI) ? lane : NI - 1;
  const int* adjrow = adj + (size_t)b * (NI * NI) + al_lane * NI + j0;
  int adjv[13];
  #pragma unroll
  for (int t = 0; t < 13; ++t) adjv[t] = (t < nj) ? adjrow[t] : 0;

  // ---- scores: e[jj] for my row vs j0+jj ----
  float e[13];
  #pragma unroll
  for (int jj = 0; jj < 13; ++jj) {
    float acc = 0.f;
    if (jj < nj) {
      int j = j0 + jj;
      int k = adjv[jj] - 1; k = (k < 0) ? 0 : (k > 3) ? 3 : k;
      const float* aw = &as[k * 100];
      #pragma unroll
      for (int q = 0; q < 25; ++q) {
        float4 hj = *(const float4*)&hl[j * 108 + q * 4];   // uniform broadcast
        float4 a4 = *(const float4*)(aw + q * 4);           // <=4 distinct addrs
        float4 hm = hreg[q];
        acc += hm.x * hj.x * a4.x + hm.y * hj.y * a4.y
             + hm.z * hj.z * a4.z + hm.w * hj.w * a4.w;
      }
      acc = (acc >= 0.f) ? acc : 0.2f * acc;     // leakyrelu
      acc = (adjv[jj] == 0) ? -9e15f : acc;      // mask (matches reference)
    } else {
      acc = -INFINITY;                           // excluded from max/sum
    }
    e[jj] = acc;
  }

  // ---- softmax across waves (per-lane row-local) ----
  float mloc = -INFINITY;
  #pragma unroll
  for (int jj = 0; jj < 13; ++jj) if (jj < nj) mloc = fmaxf(mloc, e[jj]);
  wred[w][0][lane] = mloc;
  __syncthreads();
  float m = fmaxf(fmaxf(wred[0][0][lane], wred[1][0][lane]),
                  fmaxf(wred[2][0][lane], wred[3][0][lane]));
  float sloc = 0.f;
  #pragma unroll
  for (int jj = 0; jj < 13; ++jj) if (jj < nj) {
    e[jj] = expf(e[jj] - m);
    sloc += e[jj];
  }
  wred[w][1][lane] = sloc;
  __syncthreads();
  float s = (wred[0][1][lane] + wred[1][1][lane]) +
            (wred[2][1][lane] + wred[3][1][lane]);
  float inv = 1.f / s;
  #pragma unroll
  for (int jj = 0; jj < 13; ++jj) if (jj < nj)
    alpha_lds[lane * 51 + j0 + jj] = e[jj] * inv;
  __syncthreads();

  // ---- PV: out[i][d] = sum_j alpha[i][j] * h[j][d]; wave w owns quads w+4t ----
  int nq = (w == 0) ? 7 : 6;
  float4 outq[7];
  #pragma unroll
  for (int t = 0; t < 7; ++t) outq[t] = make_float4(0.f, 0.f, 0.f, 0.f);
  for (int j = 0; j < NI; ++j) {
    float aj = alpha_lds[lane * 51 + j];        // stride 51 -> conflict-free
    #pragma unroll
    for (int t = 0; t < 7; ++t) {
      if (t < nq) {
        int q = w + 4 * t;
        float4 hv = *(const float4*)&hl[j * 108 + q * 4];   // uniform broadcast
        outq[t].x += aj * hv.x; outq[t].y += aj * hv.y;
        outq[t].z += aj * hv.z; outq[t].w += aj * hv.w;
      }
    }
  }
  if (lane < NI) {
    #pragma unroll
    for (int t = 0; t < 7; ++t) {
      if (t < nq) {
        int q = w + 4 * t;
        *(float4*)&hgat[((size_t)b * NI + lane) * EMB + q * 4] = outq[t];
      }
    }
  }
}

// ---------------- get_seq mix ----------------
__global__ void kseq(const float* __restrict__ emb, const int* __restrict__ rev,
                     const int* __restrict__ alias, const float* __restrict__ hgat,
                     float* __restrict__ hseq) {
  int idx = blockIdx.x * 256 + threadIdx.x;  // 2,560,000 exact
  int b = idx / 5000, r = idx % 5000, l = r / 100, d = r % 100;
  int node = rev[b * LL + l];
  float sh = (node == 0) ? 0.f : emb[(size_t)(node - 1) * EMB + d];
  int a = alias[b * LL + l];
  float shh = hgat[((size_t)b * NI + a) * EMB + d];
  hseq[idx] = 0.2f * sh + 0.8f * shh;
}

// ---------------- weight prep: transposes + pos@W1a ----------------
__global__ void kprep_t(const float* __restrict__ w1W, const float* __restrict__ g1W,
                        const float* __restrict__ g2W, float* __restrict__ w1t2,
                        float* __restrict__ g1t, float* __restrict__ g2t) {
  int idx = blockIdx.x * 256 + threadIdx.x;
  if (idx >= 10000) return;
  int c = idx / 100, o = idx % 100;
  w1t2[c * 100 + o] = w1W[o * 200 + 100 + c];
  g1t[c * 100 + o] = g1W[o * 100 + c];
  g2t[c * 100 + o] = g2W[o * 100 + c];
}

__global__ void kprep_pos(const float* __restrict__ posE, const float* __restrict__ w1W,
                          const float* __restrict__ w1b, float* __restrict__ posW) {
  int idx = blockIdx.x * 256 + threadIdx.x;
  if (idx >= 5000) return;
  int l = idx / 100, o = idx % 100;
  float acc = w1b[o];
  for (int c = 0; c < 100; ++c) acc += posE[l * 100 + c] * w1W[o * 200 + c];
  posW[idx] = acc;
}

// ---------------- soft attention (block per batch, register-tiled) ----------------
__global__ __launch_bounds__(256) void ksoft(
    const float* __restrict__ hseqG, const float* __restrict__ slenp,
    const int* __restrict__ maskp,
    const float* __restrict__ posW, const float* __restrict__ w1t2,
    const float* __restrict__ glu1t, const float* __restrict__ glu1b,
    const float* __restrict__ glu2t, const float* __restrict__ w2,
    float* __restrict__ sel) {
  __shared__ float hq[LL * 101];       // 20.2 KB
  __shared__ float nh[LL * 100];       // 20 KB
  __shared__ float red[25 * 52];       // 5.2 KB  (red[og][l])
  __shared__ float hs_s[100];
  __shared__ float g_s[100];
  __shared__ float beta_s[LL];
  int b = blockIdx.x, tid = threadIdx.x;
  for (int idx = tid; idx < LL * 100; idx += 256) {
    int l = idx / 100, d = idx % 100;
    hq[l * 101 + d] = hseqG[((size_t)b * LL + l) * 100 + d];
  }
  __syncthreads();
  if (tid < 100) {
    float s = 0.f;
    for (int l = 0; l < LL; ++l) s += hq[l * 101 + tid];
    hs_s[tid] = s / slenp[b];
  }
  __syncthreads();
  if (tid < 100) {
    float acc = 0.f;
    for (int c = 0; c < 100; ++c) acc += hs_s[c] * glu2t[c * 100 + tid];
    g_s[tid] = acc;
  }
  // ---- phase B: nh = tanh(hq @ w1t2 + posW) ----
  int lg = tid / 25, og = tid % 25;    // valid when tid < 250
  if (tid < 250) {
    float acc[5][4];
    #pragma unroll
    for (int j = 0; j < 5; ++j) {
      float4 p = *(const float4*)&posW[(lg * 5 + j) * 100 + og * 4];
      acc[j][0] = p.x; acc[j][1] = p.y; acc[j][2] = p.z; acc[j][3] = p.w;
    }
    for (int c = 0; c < 100; ++c) {
      float4 wv = *(const float4*)&w1t2[c * 100 + og * 4];
      float hv[5];
      #pragma unroll
      for (int j = 0; j < 5; ++j) hv[j] = hq[(lg * 5 + j) * 101 + c];
      #pragma unroll
      for (int j = 0; j < 5; ++j) {
        acc[j][0] += hv[j] * wv.x;
        acc[j][1] += hv[j] * wv.y;
        acc[j][2] += hv[j] * wv.z;
        acc[j][3] += hv[j] * wv.w;
      }
    }
    #pragma unroll
    for (int j = 0; j < 5; ++j) {
      float4 t;
      t.x = tanhf(acc[j][0]); t.y = tanhf(acc[j][1]);
      t.z = tanhf(acc[j][2]); t.w = tanhf(acc[j][3]);
      *(float4*)&nh[(lg * 5 + j) * 100 + og * 4] = t;
    }
  }
  __syncthreads();  // nh + g_s visible
  // ---- phase C: val = sigmoid(nh @ glu1t + g + b) * w2; row-sum -> red ----
  if (tid < 250) {
    float4 gb = *(const float4*)&glu1b[og * 4];
    float4 gg = *(const float4*)&g_s[og * 4];
    float base0 = gg.x + gb.x, base1 = gg.y + gb.y, base2 = gg.z + gb.z, base3 = gg.w + gb.w;
    float acc[5][4];
    #pragma unroll
    for (int j = 0; j < 5; ++j) {
      acc[j][0] = base0; acc[j][1] = base1; acc[j][2] = base2; acc[j][3] = base3;
    }
    for (int c = 0; c < 100; ++c) {
      float4 wv = *(const float4*)&glu1t[c * 100 + og * 4];
      float hv[5];
      #pragma unroll
      for (int j = 0; j < 5; ++j) hv[j] = nh[(lg * 5 + j) * 100 + c];
      #pragma unroll
      for (int j = 0; j < 5; ++j) {
        acc[j][0] += hv[j] * wv.x;
        acc[j][1] += hv[j] * wv.y;
        acc[j][2] += hv[j] * wv.z;
        acc[j][3] += hv[j] * wv.w;
      }
    }
    float4 w2v = *(const float4*)&w2[og * 4];
    #pragma unroll
    for (int j = 0; j < 5; ++j) {
      float s0 = w2v.x / (1.f + expf(-acc[j][0]));
      float s1 = w2v.y / (1.f + expf(-acc[j][1]));
      float s2 = w2v.z / (1.f + expf(-acc[j][2]));
      float s3 = w2v.w / (1.f + expf(-acc[j][3]));
      red[og * 52 + lg * 5 + j] = (s0 + s1) + (s2 + s3);
    }
  }
  __syncthreads();
  if (tid < LL) {
    float s = 0.f;
    for (int og2 = 0; og2 < 25; ++og2) s += red[og2 * 52 + tid];
    beta_s[tid] = s * (float)maskp[b * LL + tid];
  }
  __syncthreads();
  if (tid < 100) {
    float acc = 0.f;
    for (int l = 0; l < LL; ++l) acc += beta_s[l] * hq[l * 101 + tid];
    sel[(size_t)b * 100 + tid] = acc;
  }
}

// ---------------- session conv: dense [512,512] @ [512,100] ----------------
__global__ void ksess(const float* __restrict__ adjS, const float* __restrict__ x,
                      float* __restrict__ out) {
  int b = blockIdx.x, d = threadIdx.x;
  if (d >= 100) return;
  const float* ar = adjS + (size_t)b * BB;
  float a0 = 0.f, a1 = 0.f, a2 = 0.f, a3 = 0.f;
  for (int j = 0; j < BB; j += 4) {
    a0 += ar[j]     * x[(j)     * 100 + d];
    a1 += ar[j + 1] * x[(j + 1) * 100 + d];
    a2 += ar[j + 2] * x[(j + 2) * 100 + d];
    a3 += ar[j + 3] * x[(j + 3) * 100 + d];
  }
  out[(size_t)b * 100 + d] = (a0 + a1) + (a2 + a3);
}

__global__ void ksesscomb(const float* __restrict__ x0, const float* __restrict__ x1,
                          const float* __restrict__ x2, const float* __restrict__ aS,
                          float* __restrict__ out) {
  int b = blockIdx.x * 4 + (threadIdx.x >> 6);
  int lane = threadIdx.x & 63;
  int d0 = lane, d1 = lane + 64;
  bool h1 = d1 < EMB;
  size_t base = (size_t)b * EMB;
  float v00 = x0[base + d0], v01 = h1 ? x0[base + d1] : 0.f;
  float v10 = x1[base + d0], v11 = h1 ? x1[base + d1] : 0.f;
  float v20 = x2[base + d0], v21 = h1 ? x2[base + d1] : 0.f;
  float q0 = v00 * v00 + v01 * v01;
  float q1 = v10 * v10 + v11 * v11;
  float q2 = v20 * v20 + v21 * v21;
  #pragma unroll
  for (int off = 32; off; off >>= 1) {
    q0 += __shfl_xor(q0, off);
    q1 += __shfl_xor(q1, off);
    q2 += __shfl_xor(q2, off);
  }
  float r0 = 1.f / fmaxf(sqrtf(q0), 1e-12f);
  float r1 = 1.f / fmaxf(sqrtf(q1), 1e-12f);
  float r2 = 1.f / fmaxf(sqrtf(q2), 1e-12f);
  float b0 = aS[0], b1 = aS[1], b2 = aS[2];
  // seq_h = sel1+sel2 = 2 * session_conv output
  out[base + d0] = 2.f * (b0 * v00 * r0 + b1 * v10 * r1 + b2 * v20 * r2);
  if (h1) out[base + d1] = 2.f * (b0 * v01 * r0 + b1 * v11 * r1 + b2 * v21 * r2);
}

// ---------------- bf16 hi/lo split prep ----------------
// B = 2*emb_gnn -> [40000][128] padded; A = seqh -> [512][128] padded
__global__ void kprepB(const float* __restrict__ emb, unsigned short* __restrict__ bHi,
                       unsigned short* __restrict__ bLo) {
  int idx = blockIdx.x * 256 + threadIdx.x;  // 5,120,000 exact
  int n = idx >> 7, k = idx & 127;
  float v = (k < EMB) ? 2.f * emb[(size_t)n * EMB + k] : 0.f;
  __hip_bfloat16 h = __float2bfloat16(v);
  float rem = v - __bfloat162float(h);
  __hip_bfloat16 l = __float2bfloat16(rem);
  bHi[idx] = *reinterpret_cast<unsigned short*>(&h);
  bLo[idx] = *reinterpret_cast<unsigned short*>(&l);
}

__global__ void kprepA(const float* __restrict__ seqh, unsigned short* __restrict__ aHi,
                       unsigned short* __restrict__ aLo) {
  int idx = blockIdx.x * 256 + threadIdx.x;  // 65,536 exact
  int n = idx >> 7, k = idx & 127;
  float v = (k < EMB) ? seqh[(size_t)n * EMB + k] : 0.f;
  __hip_bfloat16 h = __float2bfloat16(v);
  float rem = v - __bfloat162float(h);
  __hip_bfloat16 l = __float2bfloat16(rem);
  aHi[idx] = *reinterpret_cast<unsigned short*>(&h);
  aLo[idx] = *reinterpret_cast<unsigned short*>(&l);
}

// ---------------- scores GEMM v4: v3 + fused partial-LSE ----------------
// v3 structure (64x64 tile, 2 b-steps, A up-front).  New: after each b-step's
// MFMA, a 16-lane shfl_xor reduce computes per-(row, n-block) partial
// (max, sumexp) over this block's 64 cols -> part2[nb*512+row] (each block
// writes one contiguous 1 KB window -> single-XCD, no dirty-line bounce).
// klse then only combines 625 partials/row (2.5 MB) instead of re-reading
// the 82 MB score matrix from HBM.
__global__ __launch_bounds__(256) void kscoresM(
    const unsigned short* __restrict__ aHi, const unsigned short* __restrict__ aLo,
    const unsigned short* __restrict__ bHi, const unsigned short* __restrict__ bLo,
    float* __restrict__ outS, float* __restrict__ part2) {
  __shared__ __align__(16) unsigned short Bh[64 * 136];  // 136 = 128 + 8 pad
  __shared__ __align__(16) unsigned short Bl[64 * 136];
  int tid = threadIdx.x;
  int nb = blockIdx.y;
  int n0 = nb * 64;
  int bbase = blockIdx.x * 128;          // 2 b-steps of 64 rows
  int w = tid >> 6, lane = tid & 63;
  int ln = lane & 15, quad = lane >> 4;

  // A fragments for BOTH b-steps, loaded up-front (L2-hot, 256 KB total set)
  const unsigned short* aRowH0 = aHi + (size_t)(bbase + w * 16 + ln) * 128 + quad * 8;
  const unsigned short* aRowL0 = aLo + (size_t)(bbase + w * 16 + ln) * 128 + quad * 8;
  const unsigned short* aRowH1 = aRowH0 + 64 * 128;
  const unsigned short* aRowL1 = aRowL0 + 64 * 128;
  s16x8 ah0[4], al0[4], ah1[4], al1[4];
  #pragma unroll
  for (int s = 0; s < 4; ++s) {
    ah0[s] = *(const s16x8*)(aRowH0 + s * 32);
    al0[s] = *(const s16x8*)(aRowL0 + s * 32);
    ah1[s] = *(const s16x8*)(aRowH1 + s * 32);
    al1[s] = *(const s16x8*)(aRowL1 + s * 32);
  }

  // stage B tile (64 rows x 128 k, hi+lo) into LDS -- once for both b-steps
  #pragma unroll
  for (int it = 0; it < 4; ++it) {
    int seg = tid + it * 256;      // 0..1023
    int r = seg >> 4, q = seg & 15;
    *(s16x8*)&Bh[r * 136 + q * 8] = *(const s16x8*)&bHi[(size_t)(n0 + r) * 128 + q * 8];
    *(s16x8*)&Bl[r * 136 + q * 8] = *(const s16x8*)&bLo[(size_t)(n0 + r) * 128 + q * 8];
  }
  __syncthreads();

  // ---- b-step 0 ----
  f32x4 acc[4];
  #pragma unroll
  for (int t = 0; t < 4; ++t) acc[t] = (f32x4){0.f, 0.f, 0.f, 0.f};
  #pragma unroll
  for (int s = 0; s < 4; ++s) {
    #pragma unroll
    for (int t = 0; t < 4; ++t) {
      s16x8 bh = *(const s16x8*)&Bh[(t * 16 + ln) * 136 + s * 32 + quad * 8];
      s16x8 bl = *(const s16x8*)&Bl[(t * 16 + ln) * 136 + s * 32 + quad * 8];
      acc[t] = __builtin_amdgcn_mfma_f32_16x16x32_bf16(ah0[s], bh, acc[t], 0, 0, 0);
      acc[t] = __builtin_amdgcn_mfma_f32_16x16x32_bf16(al0[s], bh, acc[t], 0, 0, 0);
      acc[t] = __builtin_amdgcn_mfma_f32_16x16x32_bf16(ah0[s], bl, acc[t], 0, 0, 0);
    }
  }
  {
    int brow = bbase + w * 16 + quad * 4;
    #pragma unroll
    for (int t = 0; t < 4; ++t) {
      int ncol = n0 + t * 16 + ln;
      #pragma unroll
      for (int r = 0; r < 4; ++r) {
        outS[(size_t)(brow + r) * N_NODE + ncol] = acc[t][r];
      }
    }
    // partial LSE over this block's 64 cols for rows brow..brow+3
    #pragma unroll
    for (int r = 0; r < 4; ++r) {
      float mx = fmaxf(fmaxf(acc[0][r], acc[1][r]), fmaxf(acc[2][r], acc[3][r]));
      #pragma unroll
      for (int off = 1; off < 16; off <<= 1) mx = fmaxf(mx, __shfl_xor(mx, off));
      float se = expf(acc[0][r] - mx) + expf(acc[1][r] - mx)
               + expf(acc[2][r] - mx) + expf(acc[3][r] - mx);
      #pragma unroll
      for (int off = 1; off < 16; off <<= 1) se += __shfl_xor(se, off);
      if (ln == 0) {
        float2 p; p.x = mx; p.y = se;
        *(float2*)&part2[((size_t)nb * BB + brow + r) * 2] = p;
      }
    }
  }

  // ---- b-step 1 ----
  #pragma unroll
  for (int t = 0; t < 4; ++t) acc[t] = (f32x4){0.f, 0.f, 0.f, 0.f};
  #pragma unroll
  for (int s = 0; s < 4; ++s) {
    #pragma unroll
    for (int t = 0; t < 4; ++t) {
      s16x8 bh = *(const s16x8*)&Bh[(t * 16 + ln) * 136 + s * 32 + quad * 8];
      s16x8 bl = *(const s16x8*)&Bl[(t * 16 + ln) * 136 + s * 32 + quad * 8];
      acc[t] = __builtin_amdgcn_mfma_f32_16x16x32_bf16(ah1[s], bh, acc[t], 0, 0, 0);
      acc[t] = __builtin_amdgcn_mfma_f32_16x16x32_bf16(al1[s], bh, acc[t], 0, 0, 0);
      acc[t] = __builtin_amdgcn_mfma_f32_16x16x32_bf16(ah1[s], bl, acc[t], 0, 0, 0);
    }
  }
  {
    int brow = bbase + 64 + w * 16 + quad * 4;
    #pragma unroll
    for (int t = 0; t < 4; ++t) {
      int ncol = n0 + t * 16 + ln;
      #pragma unroll
      for (int r = 0; r < 4; ++r) {
        outS[(size_t)(brow + r) * N_NODE + ncol] = acc[t][r];
      }
    }
    #pragma unroll
    for (int r = 0; r < 4; ++r) {
      float mx = fmaxf(fmaxf(acc[0][r], acc[1][r]), fmaxf(acc[2][r], acc[3][r]));
      #pragma unroll
      for (int off = 1; off < 16; off <<= 1) mx = fmaxf(mx, __shfl_xor(mx, off));
      float se = expf(acc[0][r] - mx) + expf(acc[1][r] - mx)
               + expf(acc[2][r] - mx) + expf(acc[3][r] - mx);
      #pragma unroll
      for (int off = 1; off < 16; off <<= 1) se += __shfl_xor(se, off);
      if (ln == 0) {
        float2 p; p.x = mx; p.y = se;
        *(float2*)&part2[((size_t)nb * BB + brow + r) * 2] = p;
      }
    }
  }
}

// ---------------- LSE combine over 625 partials per row + target ----------------
__global__ __launch_bounds__(256) void klse2(const float* __restrict__ part2,
                                             const float* __restrict__ outS,
                                             const int* __restrict__ tar,
                                             float* __restrict__ part) {
  __shared__ float ms[256], ss[256];
  int b = blockIdx.x, tid = threadIdx.x;
  float m = -INFINITY, s = 0.f;
  for (int nb = tid; nb < NBLK; nb += 256) {
    float2 p = *(const float2*)&part2[((size_t)nb * BB + b) * 2];
    float M = fmaxf(m, p.x);
    s = s * expf(m - M) + p.y * expf(p.x - M);
    m = M;
  }
  ms[tid] = m; ss[tid] = s;
  __syncthreads();
  for (int st = 128; st; st >>= 1) {
    if (tid < st) {
      float m2 = ms[tid + st], s2 = ss[tid + st];
      float M = fmaxf(ms[tid], m2);
      ss[tid] = ss[tid] * expf(ms[tid] - M) + s2 * expf(m2 - M);
      ms[tid] = M;
    }
    __syncthreads();
  }
  if (tid == 0) {
    float tsc = outS[(size_t)b * N_NODE + tar[b]];
    part[b] = tsc - (ms[0] + logf(ss[0]));
  }
}

__global__ void kfinal(const float* __restrict__ part, float* __restrict__ out) {
  __shared__ float red[256];
  int tid = threadIdx.x;
  red[tid] = part[tid] + part[tid + 256];
  __syncthreads();
  for (int st = 128; st; st >>= 1) {
    if (tid < st) red[tid] += red[tid + st];
    __syncthreads();
  }
  if (tid == 0) {
    out[0] = 0.f;                        // con_loss
    out[1] = -red[0] / (float)BB;        // loss
  }
}

extern "C" void kernel_launch(void* const* d_in, const int* in_sizes, int n_in,
                              void* d_out, int out_size, void* d_ws, size_t ws_size,
                              hipStream_t stream) {
  const int* tar    = (const int*)d_in[0];
  const int* rev    = (const int*)d_in[1];
  const int* maskp  = (const int*)d_in[2];
  const float* slen = (const float*)d_in[3];
  const float* sadj = (const float*)d_in[4];
  const int* items  = (const int*)d_in[6];
  const int* adjp   = (const int*)d_in[7];
  const int* alias  = (const int*)d_in[8];
  const int* grows  = (const int*)d_in[9];
  const int* gcols  = (const int*)d_in[10];
  const float* gvals = (const float*)d_in[11];
  const float* nemb = (const float*)d_in[12];
  const float* bI   = (const float*)d_in[13];
  const float* aS   = (const float*)d_in[14];
  const float* a0p  = (const float*)d_in[15];
  const float* a1p  = (const float*)d_in[16];
  const float* a2p  = (const float*)d_in[17];
  const float* a3p  = (const float*)d_in[18];
  const float* w1W  = (const float*)d_in[19];
  const float* w1b  = (const float*)d_in[20];
  const float* w2p  = (const float*)d_in[21];
  const float* g1W  = (const float*)d_in[22];
  const float* g1b  = (const float*)d_in[23];
  const float* g2W  = (const float*)d_in[24];
  const float* posE = (const float*)d_in[25];

  float* W = (float*)d_ws;
  size_t o = 0;
  float* emb_gnn = W + o; o += (size_t)N_NODE * EMB;   // 4,000,000
  float* x1      = W + o; o += (size_t)N_NODE * EMB;   // reused: hgat, then bHi
  float* x2      = W + o; o += (size_t)N_NODE * EMB;   // reused: hseq, then bLo
  float* sel     = W + o; o += (size_t)BB * EMB;
  float* y1      = W + o; o += (size_t)BB * EMB;
  float* y2      = W + o; o += (size_t)BB * EMB;
  float* seqh    = W + o; o += (size_t)BB * EMB;
  float* posW    = W + o; o += 5120;
  float* w1t2    = W + o; o += 10000;
  float* glu1t   = W + o; o += 10000;
  float* glu2t   = W + o; o += 10000;
  int2* colval   = (int2*)(W + o); o += (size_t)2 * EDG;  // merged {col,val}
  float* part    = W + o; o += 512;
  float* part2   = W + o; o += (size_t)NBLK * BB * 2;   // 640,000 floats
  int* counts = (int*)(W + o); o += N_NODE;
  int* starts = (int*)(W + o); o += N_NODE;
  int* cursor = (int*)(W + o); o += N_NODE;
  int* scantmp = (int*)(W + o); o += N_NODE;
  int* blocksums = (int*)(W + o); o += 256;
  unsigned short* aHi = (unsigned short*)(W + o); o += 32768;  // 512*128 bf16 = 32768 floats/2
  unsigned short* aLo = (unsigned short*)(W + o); o += 32768;
  // hgat/hseq alias x1/x2 (dead after kcomb); bHi/bLo alias x1/x2 (hgat dead after
  // kseq, hseq dead after ksoft; each needs 2.56M floats of the 4M region)
  float* hgat = x1;
  float* hseq = x2;
  unsigned short* bHi = (unsigned short*)x1;   // 5.12M u16 = 2.56M floats <= 4M
  unsigned short* bLo = (unsigned short*)x2;

  float* outF = (float*)d_out;
  float* outScores = outF + 2;

  hipMemsetAsync(counts, 0, N_NODE * sizeof(int), stream);
  khist<<<EDG / 256, 256, 0, stream>>>(grows, counts);
  kscan1<<<SCAN_BLOCKS, 256, 0, stream>>>(counts, scantmp, blocksums, N_NODE);
  kscan2<<<1, 256, 0, stream>>>(blocksums, SCAN_BLOCKS);
  kscan3<<<SCAN_BLOCKS, 256, 0, stream>>>(scantmp, blocksums, starts, cursor, N_NODE);
  kfill<<<((EDG + 1023) / 1024) * 8, 256, 0, stream>>>(grows, gcols, gvals, cursor, colval);
  kspmm<<<N_NODE / 4, 256, 0, stream>>>(starts, counts, colval, nemb, x1);
  kspmm<<<N_NODE / 4, 256, 0, stream>>>(starts, counts, colval, x1, x2);
  kcomb<<<N_NODE / 4, 256, 0, stream>>>(nemb, x1, x2, bI, emb_gnn);
  kgat<<<BB, 256, 0, stream>>>(emb_gnn, items, adjp, a0p, a1p, a2p, a3p, hgat);
  kseq<<<(BB * LL * EMB) / 256, 256, 0, stream>>>(emb_gnn, rev, alias, hgat, hseq);
  kprep_t<<<40, 256, 0, stream>>>(w1W, g1W, g2W, w1t2, glu1t, glu2t);
  kprep_pos<<<20, 256, 0, stream>>>(posE, w1W, w1b, posW);
  ksoft<<<BB, 256, 0, stream>>>(hseq, slen, maskp, posW, w1t2, glu1t, g1b, glu2t, w2p, sel);
  // hgat(x1) dead after kseq, hseq(x2) dead after ksoft -> safe to build bHi/bLo now
  kprepB<<<(N_NODE * 128) / 256, 256, 0, stream>>>(emb_gnn, bHi, bLo);
  ksess<<<BB, 128, 0, stream>>>(sadj, sel, y1);
  ksess<<<BB, 128, 0, stream>>>(sadj, y1, y2);
  ksesscomb<<<BB / 4, 256, 0, stream>>>(sel, y1, y2, aS, seqh);
  kprepA<<<(BB * 128) / 256, 256, 0, stream>>>(seqh, aHi, aLo);
  kscoresM<<<dim3(4, NBLK), 256, 0, stream>>>(aHi, aLo, bHi, bLo, outScores, part2);
  klse2<<<BB, 256, 0, stream>>>(part2, outScores, tar, part);
  kfinal<<<1, 256, 0, stream>>>(part, outF);
}